// Round 13
// baseline (2240.587 us; speedup 1.0000x reference)
//
#include <hip/hip_runtime.h>

// ---------------------------------------------------------------------------
// AttentionDecoder: B=64 T=32 S=64 H=1024 V=32000
// R13: R12 with ONE k_rec change: Ph1/Ph3 GEMMs load the A-operand DIRECTLY
//      from global into MFMA registers (16B/lane contiguous fragments),
//      eliminating the LDS A-staging and its 48 __syncthreads per step.
//      B (weights) stays LDS-resident. 2-deep named-buffer pipeline.
//      Everything else (phases, barriers, coherence, tail kernels) = R12.
// ---------------------------------------------------------------------------

#define B_ 64
#define T_ 32
#define S_ 64
#define H_ 1024
#define V_ 32000
#define NB_ 256
#define LDS_BYTES 152064

#define HID_OFF 65536000L
#define ATT_OFF 65601536L
#define CTF_OFF 65732608L

typedef __attribute__((ext_vector_type(8))) short bf16x8;
typedef __attribute__((ext_vector_type(4))) float f32x4;
typedef __attribute__((ext_vector_type(4))) unsigned int u32x4;
typedef unsigned short u16;
typedef unsigned long long u64;

__device__ __forceinline__ u16 f2bf(float v) {
  unsigned int u = __float_as_uint(v);
  unsigned int r = (u + 0x7fffu + ((u >> 16) & 1u)) >> 16;  // RNE
  return (u16)r;
}
__device__ __forceinline__ float bf2f(u16 h) {
  return __uint_as_float(((unsigned int)h) << 16);
}
__device__ __forceinline__ void split2(float v, u16* hi, u16* lo) {
  u16 h = f2bf(v);
  *hi = h;
  *lo = f2bf(v - bf2f(h));
}

// ---- coherent-path (agent-scope relaxed atomic) helpers ----
__device__ __forceinline__ u64 aload_u64(const void* p) {
  return __hip_atomic_load((const u64*)p, __ATOMIC_RELAXED, __HIP_MEMORY_SCOPE_AGENT);
}
__device__ __forceinline__ unsigned aload_u32(const void* p) {
  return __hip_atomic_load((const unsigned*)p, __ATOMIC_RELAXED, __HIP_MEMORY_SCOPE_AGENT);
}
__device__ __forceinline__ void astore_u64(void* p, u64 v) {
  __hip_atomic_store((u64*)p, v, __ATOMIC_RELAXED, __HIP_MEMORY_SCOPE_AGENT);
}
__device__ __forceinline__ void astore_f32(float* p, float v) {
  __hip_atomic_store((unsigned*)p, __float_as_uint(v), __ATOMIC_RELAXED,
                     __HIP_MEMORY_SCOPE_AGENT);
}

// ---- async global->LDS (16B/lane) ----
__device__ __forceinline__ void gll16(const u16* g, u16* l) {
  __builtin_amdgcn_global_load_lds(
      (const __attribute__((address_space(1))) void*)g,
      (__attribute__((address_space(3))) void*)l, 16, 0, 0);
}

// ---------------- conversion / prep kernels ----------------

__global__ void k_split4(const float* __restrict__ sA, u16* __restrict__ hA,
                         u16* __restrict__ lA, int nA,
                         const float* __restrict__ sB, u16* __restrict__ hB,
                         u16* __restrict__ lB, int nB,
                         const float* __restrict__ sC, u16* __restrict__ hC,
                         u16* __restrict__ lC, int nC,
                         const float* __restrict__ sD, u16* __restrict__ hD,
                         u16* __restrict__ lD, int nD) {
  int i = blockIdx.x * blockDim.x + threadIdx.x;
  int stride = gridDim.x * blockDim.x;
  int t1 = nA, t2 = nA + nB, t3 = t2 + nC, total = t3 + nD;
  for (; i < total; i += stride) {
    if (i < t1) split2(sA[i], &hA[i], &lA[i]);
    else if (i < t2) { int j = i - t1; split2(sB[j], &hB[j], &lB[j]); }
    else if (i < t3) { int j = i - t2; split2(sC[j], &hC[j], &lC[j]); }
    else { int j = i - t3; split2(sD[j], &hD[j], &lD[j]); }
  }
}

__global__ void k_tobf(const float* __restrict__ src, u16* __restrict__ dst, int n) {
  int i = blockIdx.x * blockDim.x + threadIdx.x;
  int stride = gridDim.x * blockDim.x;
  for (; i < n; i += stride) dst[i] = f2bf(src[i]);
}

// l1 (H,H) row-major [i][k] -> l1T hi/lo [k][i]
__global__ void k_l1t(const float* __restrict__ l1, u16* __restrict__ hi,
                      u16* __restrict__ lo) {
  __shared__ float tile[64][65];
  int it = blockIdx.x & 15, kt = blockIdx.x >> 4;
  for (int q = 0; q < 16; ++q) {
    int idx = q * 256 + threadIdx.x;
    int r = idx >> 6, c = idx & 63;
    tile[r][c] = l1[(long)(it * 64 + r) * H_ + kt * 64 + c];
  }
  __syncthreads();
  for (int q = 0; q < 16; ++q) {
    int idx = q * 256 + threadIdx.x;
    int r = idx >> 6, c = idx & 63;
    long o = (long)(kt * 64 + r) * H_ + it * 64 + c;
    split2(tile[c][r], &hi[o], &lo[o]);
  }
}

// gather embeddings: embx[t][b][k] hi/lo
__global__ void k_embx(const int* __restrict__ inp, const float* __restrict__ emb,
                       u16* __restrict__ hi, u16* __restrict__ lo) {
  int bt = blockIdx.x;
  int b = bt >> 5, t = bt & 31;
  int id = inp[b * T_ + t];
  const float* src = emb + (long)id * H_;
  long base = (long)(t * B_ + b) * H_;
  for (int k = threadIdx.x; k < H_; k += 256) split2(src[k], &hi[base + k], &lo[base + k]);
}

// h0 -> hh_r/hl_r slot 0
__global__ void k_h0(const float* __restrict__ mem, u16* __restrict__ hh,
                     u16* __restrict__ hl) {
  int i = blockIdx.x * 256 + threadIdx.x;  // 65536
  float v = mem[i];
  split2(v, &hh[i], &hl[i]);
}

__global__ void k_guard(float* out, float v) {
  if (blockIdx.x == 0 && threadIdx.x == 0) out[0] = v;
}

// ------- prep GEMM: 128x128 tile, K=1024, split-bf16, gll16 staging -------
__launch_bounds__(256)
__global__ void k_gemmG(const u16* __restrict__ Ah, const u16* __restrict__ Al,
                        const u16* __restrict__ Bh, const u16* __restrict__ Bl,
                        float* __restrict__ C, int Mtiles, int Arow, int Brow,
                        int Crow) {
  int bx = blockIdx.x;
  int mt = bx % Mtiles, nt = bx / Mtiles;
  int m0 = mt << 7, n0 = nt << 7;

  __shared__ __attribute__((aligned(16))) u16 lds[4 * 4096];  // 32 KB
  char* L = (char*)lds;
  const int tid = threadIdx.x;
  const int lane = tid & 63, wid = tid >> 6;
  const int wm = wid & 1, wn = wid >> 1;
  const int l15 = lane & 15, kq = lane >> 4;

  const int r8 = lane >> 2, ss = lane & 3;
  const int rA0 = (wid << 4) + r8, rA1 = rA0 + 64;
  const int sw0 = (ss ^ (rA0 & 3)) << 3, sw1 = (ss ^ (rA1 & 3)) << 3;
  const u16* gAh0 = Ah + (long)(m0 + rA0) * Arow + sw0;
  const u16* gAh1 = Ah + (long)(m0 + rA1) * Arow + sw1;
  const u16* gAl0 = Al + (long)(m0 + rA0) * Arow + sw0;
  const u16* gAl1 = Al + (long)(m0 + rA1) * Arow + sw1;
  const u16* gBh0 = Bh + (long)(n0 + rA0) * Brow + sw0;
  const u16* gBh1 = Bh + (long)(n0 + rA1) * Brow + sw1;
  const u16* gBl0 = Bl + (long)(n0 + rA0) * Brow + sw0;
  const u16* gBl1 = Bl + (long)(n0 + rA1) * Brow + sw1;
  u16* dAh0 = (u16*)(L + (wid << 10));
  u16* dAh1 = (u16*)(L + 4096 + (wid << 10));
  u16* dBh0 = (u16*)(L + 8192 + (wid << 10));
  u16* dBh1 = (u16*)(L + 12288 + (wid << 10));
  u16* dAl0 = (u16*)(L + 16384 + (wid << 10));
  u16* dAl1 = (u16*)(L + 20480 + (wid << 10));
  u16* dBl0 = (u16*)(L + 24576 + (wid << 10));
  u16* dBl1 = (u16*)(L + 28672 + (wid << 10));

  f32x4 acc[4][4];
  const f32x4 z4 = {0.f, 0.f, 0.f, 0.f};
#pragma unroll
  for (int i = 0; i < 4; ++i)
#pragma unroll
    for (int j = 0; j < 4; ++j) acc[i][j] = z4;

  for (int kt = 0; kt < 32; ++kt) {
    __syncthreads();
    int ko = kt << 5;
    gll16(gAh0 + ko, dAh0);
    gll16(gAh1 + ko, dAh1);
    gll16(gBh0 + ko, dBh0);
    gll16(gBh1 + ko, dBh1);
    gll16(gAl0 + ko, dAl0);
    gll16(gAl1 + ko, dAl1);
    gll16(gBl0 + ko, dBl0);
    gll16(gBl1 + ko, dBl1);
    __syncthreads();
    bf16x8 aH[4], bH[4], aL[4], bL[4];
#pragma unroll
    for (int mi = 0; mi < 4; ++mi) {
      int r = (wm << 6) + (mi << 4) + l15;
      int off = r * 64 + ((kq ^ (r & 3)) << 4);
      aH[mi] = *(const bf16x8*)(L + off);
      aL[mi] = *(const bf16x8*)(L + 16384 + off);
    }
#pragma unroll
    for (int ni = 0; ni < 4; ++ni) {
      int c = (wn << 6) + (ni << 4) + l15;
      int off = c * 64 + ((kq ^ (c & 3)) << 4);
      bH[ni] = *(const bf16x8*)(L + 8192 + off);
      bL[ni] = *(const bf16x8*)(L + 24576 + off);
    }
#pragma unroll
    for (int mi = 0; mi < 4; ++mi)
#pragma unroll
      for (int ni = 0; ni < 4; ++ni) {
        acc[mi][ni] = __builtin_amdgcn_mfma_f32_16x16x32_bf16(aH[mi], bH[ni], acc[mi][ni], 0, 0, 0);
        acc[mi][ni] = __builtin_amdgcn_mfma_f32_16x16x32_bf16(aL[mi], bH[ni], acc[mi][ni], 0, 0, 0);
        acc[mi][ni] = __builtin_amdgcn_mfma_f32_16x16x32_bf16(aH[mi], bL[ni], acc[mi][ni], 0, 0, 0);
      }
  }
#pragma unroll
  for (int mi = 0; mi < 4; ++mi)
#pragma unroll
    for (int ni = 0; ni < 4; ++ni)
#pragma unroll
      for (int e = 0; e < 4; ++e) {
        int r = (wm << 6) + (mi << 4) + (kq << 2) + e;
        int c = (wn << 6) + (ni << 4) + l15;
        C[(long)(m0 + r) * Crow + n0 + c] = acc[mi][ni][e];
      }
}

__device__ __forceinline__ void lse_comb(float& m, float& s, float mo, float so) {
  float M = fmaxf(m, mo);
  s = s * __expf(m - M) + so * __expf(mo - M);
  m = M;
}

// ---------------- logits GEMM + partial-LSE epilogue ----------------
__launch_bounds__(256)
__global__ void k_gemmL(const u16* __restrict__ A, const u16* __restrict__ Bw,
                        const float* __restrict__ bias, float* __restrict__ C,
                        float2* __restrict__ psum) {
  int bx = blockIdx.x;
  int wg = (bx & 7) * 500 + (bx >> 3);  // XCD-contiguous
  int mt = wg & 15, nt = wg >> 4;
  int m0 = mt << 7, n0 = nt << 7;

  __shared__ __attribute__((aligned(16))) u16 lds[2 * 4096];  // 16 KB
  __shared__ float2 lsep[128][2];
  char* L = (char*)lds;
  const int tid = threadIdx.x;
  const int lane = tid & 63, wid = tid >> 6;
  const int wm = wid & 1, wn = wid >> 1;
  const int l15 = lane & 15, kq = lane >> 4;

  const int r8 = lane >> 2, ss = lane & 3;
  const int rA0 = (wid << 4) + r8, rA1 = rA0 + 64;
  const u16* gA0 = A + (long)(m0 + rA0) * 1024 + ((ss ^ (rA0 & 3)) << 3);
  const u16* gA1 = A + (long)(m0 + rA1) * 1024 + ((ss ^ (rA1 & 3)) << 3);
  const u16* gB0 = Bw + (long)(n0 + rA0) * 1024 + ((ss ^ (rA0 & 3)) << 3);
  const u16* gB1 = Bw + (long)(n0 + rA1) * 1024 + ((ss ^ (rA1 & 3)) << 3);
  u16* lA0 = (u16*)(L + (wid << 10));
  u16* lA1 = (u16*)(L + 4096 + (wid << 10));
  u16* lB0 = (u16*)(L + 8192 + (wid << 10));
  u16* lB1 = (u16*)(L + 12288 + (wid << 10));

  f32x4 acc[4][4];
  const f32x4 z4 = {0.f, 0.f, 0.f, 0.f};
#pragma unroll
  for (int i = 0; i < 4; ++i)
#pragma unroll
    for (int j = 0; j < 4; ++j) acc[i][j] = z4;

  for (int kt = 0; kt < 32; ++kt) {
    __syncthreads();
    gll16(gA0 + (kt << 5), lA0);
    gll16(gA1 + (kt << 5), lA1);
    gll16(gB0 + (kt << 5), lB0);
    gll16(gB1 + (kt << 5), lB1);
    __syncthreads();
    bf16x8 aF[4], bF[4];
#pragma unroll
    for (int mi = 0; mi < 4; ++mi) {
      int r = (wm << 6) + (mi << 4) + l15;
      aF[mi] = *(const bf16x8*)(L + r * 64 + ((kq ^ (r & 3)) << 4));
    }
#pragma unroll
    for (int ni = 0; ni < 4; ++ni) {
      int c = (wn << 6) + (ni << 4) + l15;
      bF[ni] = *(const bf16x8*)(L + 8192 + c * 64 + ((kq ^ (c & 3)) << 4));
    }
#pragma unroll
    for (int mi = 0; mi < 4; ++mi)
#pragma unroll
      for (int ni = 0; ni < 4; ++ni)
        acc[mi][ni] = __builtin_amdgcn_mfma_f32_16x16x32_bf16(aF[mi], bF[ni], acc[mi][ni], 0, 0, 0);
  }
  float b4[4];
#pragma unroll
  for (int ni = 0; ni < 4; ++ni) b4[ni] = bias[n0 + (wn << 6) + (ni << 4) + l15];
#pragma unroll
  for (int mi = 0; mi < 4; ++mi)
#pragma unroll
    for (int e = 0; e < 4; ++e) {
      int r = (wm << 6) + (mi << 4) + (kq << 2) + e;
      int gm = m0 + r;
      float vv[4], vm = -3.0e38f, vs = 0.f;
#pragma unroll
      for (int ni = 0; ni < 4; ++ni) {
        vv[ni] = acc[mi][ni][e] + b4[ni];
        vm = fmaxf(vm, vv[ni]);
      }
#pragma unroll
      for (int ni = 0; ni < 4; ++ni) {
        vs += __expf(vv[ni] - vm);
        int gn = n0 + (wn << 6) + (ni << 4) + l15;
        C[((long)(gm & 63) * T_ + (gm >> 6)) * V_ + gn] = vv[ni];
      }
#pragma unroll
      for (int o = 1; o < 16; o <<= 1) {
        float mo = __shfl_xor(vm, o), so = __shfl_xor(vs, o);
        lse_comb(vm, vs, mo, so);
      }
      if (l15 == 0) lsep[r][wn] = make_float2(vm, vs);
    }
  __syncthreads();
  if (tid < 128) {
    float2 a = lsep[tid][0], b2 = lsep[tid][1];
    float M = a.x, S = a.y;
    lse_comb(M, S, b2.x, b2.y);
    psum[((long)(m0 + tid) << 8) + nt] = make_float2(M, S);
  }
}

// ---------------- grid barrier (R7 verbatim) ----------------
__device__ __forceinline__ void gridbar(unsigned* flags, unsigned seq) {
  __syncthreads();
  if (threadIdx.x == 0)
    __hip_atomic_store(flags + blockIdx.x * 16, seq, __ATOMIC_RELEASE,
                       __HIP_MEMORY_SCOPE_AGENT);
  if (threadIdx.x < 64) {
    int l = threadIdx.x;
    for (;;) {
      unsigned a = __hip_atomic_load(flags + l * 16, __ATOMIC_RELAXED, __HIP_MEMORY_SCOPE_AGENT);
      unsigned b = __hip_atomic_load(flags + (l + 64) * 16, __ATOMIC_RELAXED, __HIP_MEMORY_SCOPE_AGENT);
      unsigned c = __hip_atomic_load(flags + (l + 128) * 16, __ATOMIC_RELAXED, __HIP_MEMORY_SCOPE_AGENT);
      unsigned d = __hip_atomic_load(flags + (l + 192) * 16, __ATOMIC_RELAXED, __HIP_MEMORY_SCOPE_AGENT);
      if (__all((a >= seq) & (b >= seq) & (c >= seq) & (d >= seq))) break;
      __builtin_amdgcn_s_sleep(1);
    }
  }
  __syncthreads();
}

// ---- direct-A GEMM vs LDS-resident W: no barriers, 2-deep pipeline ----
// NI=2: 64-col out (gi/gh); NI=1: 32-col (l2b). NST = K/32 subtiles.
template <int NI, int NST>
__device__ __forceinline__ void gemm_dir(const u16* __restrict__ Ah,
                                         const u16* __restrict__ Al,
                                         const char* W_HI, const char* W_LO,
                                         int wm, int wn, int l15, int kq,
                                         f32x4 (&acc)[2][NI]) {
  const int wsub = (NI == 2) ? 4096 : 2048;
  const long ra0 = (long)((wm << 5) + l15) * 1024 + (kq << 3);
  const long ra1 = ra0 + (16L * 1024);
  bf16x8 eAh0, eAh1, eAl0, eAl1;  // even-st stage
  bf16x8 oAh0, oAh1, oAl0, oAl1;  // odd-st stage
  eAh0 = *(const bf16x8*)(Ah + ra0);
  eAh1 = *(const bf16x8*)(Ah + ra1);
  eAl0 = *(const bf16x8*)(Al + ra0);
  eAl1 = *(const bf16x8*)(Al + ra1);
  oAh0 = *(const bf16x8*)(Ah + ra0 + 32);
  oAh1 = *(const bf16x8*)(Ah + ra1 + 32);
  oAl0 = *(const bf16x8*)(Al + ra0 + 32);
  oAl1 = *(const bf16x8*)(Al + ra1 + 32);
#pragma unroll
  for (int st = 0; st < NST; st += 2) {
    {
      const int stw = st * wsub;
      bf16x8 bH[NI], bL[NI];
#pragma unroll
      for (int ni = 0; ni < NI; ++ni) {
        int c = (wn << (NI == 2 ? 5 : 4)) + (ni << 4) + l15;
        int off = c * 64 + ((kq ^ (c & 3)) << 4);
        bH[ni] = *(const bf16x8*)(W_HI + stw + off);
        bL[ni] = *(const bf16x8*)(W_LO + stw + off);
      }
#pragma unroll
      for (int ni = 0; ni < NI; ++ni) {
        acc[0][ni] = __builtin_amdgcn_mfma_f32_16x16x32_bf16(eAh0, bH[ni], acc[0][ni], 0, 0, 0);
        acc[0][ni] = __builtin_amdgcn_mfma_f32_16x16x32_bf16(eAl0, bH[ni], acc[0][ni], 0, 0, 0);
        acc[0][ni] = __builtin_amdgcn_mfma_f32_16x16x32_bf16(eAh0, bL[ni], acc[0][ni], 0, 0, 0);
        acc[1][ni] = __builtin_amdgcn_mfma_f32_16x16x32_bf16(eAh1, bH[ni], acc[1][ni], 0, 0, 0);
        acc[1][ni] = __builtin_amdgcn_mfma_f32_16x16x32_bf16(eAl1, bH[ni], acc[1][ni], 0, 0, 0);
        acc[1][ni] = __builtin_amdgcn_mfma_f32_16x16x32_bf16(eAh1, bL[ni], acc[1][ni], 0, 0, 0);
      }
    }
    if (st + 2 < NST) {
      long o = ra0 + (long)(st + 2) * 32;
      eAh0 = *(const bf16x8*)(Ah + o);
      eAh1 = *(const bf16x8*)(Ah + o + 16L * 1024);
      eAl0 = *(const bf16x8*)(Al + o);
      eAl1 = *(const bf16x8*)(Al + o + 16L * 1024);
    }
    {
      const int stw = (st + 1) * wsub;
      bf16x8 bH[NI], bL[NI];
#pragma unroll
      for (int ni = 0; ni < NI; ++ni) {
        int c = (wn << (NI == 2 ? 5 : 4)) + (ni << 4) + l15;
        int off = c * 64 + ((kq ^ (c & 3)) << 4);
        bH[ni] = *(const bf16x8*)(W_HI + stw + off);
        bL[ni] = *(const bf16x8*)(W_LO + stw + off);
      }
#pragma unroll
      for (int ni = 0; ni < NI; ++ni) {
        acc[0][ni] = __builtin_amdgcn_mfma_f32_16x16x32_bf16(oAh0, bH[ni], acc[0][ni], 0, 0, 0);
        acc[0][ni] = __builtin_amdgcn_mfma_f32_16x16x32_bf16(oAl0, bH[ni], acc[0][ni], 0, 0, 0);
        acc[0][ni] = __builtin_amdgcn_mfma_f32_16x16x32_bf16(oAh0, bL[ni], acc[0][ni], 0, 0, 0);
        acc[1][ni] = __builtin_amdgcn_mfma_f32_16x16x32_bf16(oAh1, bH[ni], acc[1][ni], 0, 0, 0);
        acc[1][ni] = __builtin_amdgcn_mfma_f32_16x16x32_bf16(oAl1, bH[ni], acc[1][ni], 0, 0, 0);
        acc[1][ni] = __builtin_amdgcn_mfma_f32_16x16x32_bf16(oAh1, bL[ni], acc[1][ni], 0, 0, 0);
      }
    }
    if (st + 3 < NST) {
      long o = ra0 + (long)(st + 3) * 32;
      oAh0 = *(const bf16x8*)(Ah + o);
      oAh1 = *(const bf16x8*)(Ah + o + 16L * 1024);
      oAl0 = *(const bf16x8*)(Al + o);
      oAl1 = *(const bf16x8*)(Al + o + 16L * 1024);
    }
  }
}

// ---------------- persistent recurrence kernel ----------------
__launch_bounds__(256)
__global__ void k_rec(const float* __restrict__ embi,
                      u16* __restrict__ dctx_h, u16* __restrict__ dctx_l,
                      u16* __restrict__ hh_r, u16* __restrict__ hl_r,
                      const float* __restrict__ memory,
                      const u16* __restrict__ wih_h, const u16* __restrict__ wih_l,
                      const u16* __restrict__ whh_h, const u16* __restrict__ whh_l,
                      const u16* __restrict__ l2_h, const u16* __restrict__ l2_l,
                      float* __restrict__ gip, float* __restrict__ ghp,
                      float* __restrict__ psc, float* __restrict__ ctxp,
                      const float* __restrict__ encT, const float* __restrict__ encL,
                      const int* __restrict__ xs_len,
                      const float* __restrict__ bih, const float* __restrict__ bhh,
                      float* __restrict__ dout, unsigned* flags) {
  extern __shared__ __attribute__((aligned(16))) char L[];
  char* W_HI = L;
  char* W_LO = L + 65536;
  float* hq = (float*)(L + 147456);
  float* at_s = (float*)(L + 148480);
  const int bx = blockIdx.x;
  const int tid = threadIdx.x;
  const int lane = tid & 63, wid = tid >> 6;
  const int wm = wid & 1, wn = wid >> 1;
  const int l15 = lane & 15, kq = lane >> 4;
  const f32x4 z4 = {0.f, 0.f, 0.f, 0.f};
  unsigned seq = 1;

  const int isGI = (bx < 96);
  const int isGH = (bx >= 96 && bx < 192);
  const int isL2 = (bx >= 192 && bx < 224);
  const int sb = bx >> 2;
  const int sq = bx & 3;
  int nt = 0, kc = 0, n0 = 0;
  const u16 *Wg_h = nullptr, *Wg_l = nullptr;
  int wrs = 0;
  if (isGI) {
    nt = bx % 48; kc = bx / 48;
    Wg_h = wih_h + 1024 + (long)nt * 64 * 2048 + kc * 512;
    Wg_l = wih_l + 1024 + (long)nt * 64 * 2048 + kc * 512;
    wrs = 2048;
  } else if (isGH) {
    int j2 = bx - 96;
    nt = j2 % 48; kc = j2 / 48;
    Wg_h = whh_h + (long)nt * 64 * 1024 + kc * 512;
    Wg_l = whh_l + (long)nt * 64 * 1024 + kc * 512;
    wrs = 1024;
  } else if (isL2) {
    n0 = (bx - 192) << 5;
    Wg_h = l2_h + 1024 + (long)n0 * 2048;
    Wg_l = l2_l + 1024 + (long)n0 * 2048;
    wrs = 2048;
  }

  if (isGI || isGH) {
    for (int e = tid; e < 4096; e += 256) {
      int st = e >> 8, r = (e >> 2) & 63, slot = e & 3;
      long g = (long)r * wrs + st * 32 + slot * 8;
      int o = st * 4096 + r * 64 + ((slot ^ (r & 3)) << 4);
      *(u32x4*)(W_HI + o) = *(const u32x4*)(Wg_h + g);
      *(u32x4*)(W_LO + o) = *(const u32x4*)(Wg_l + g);
    }
  } else if (isL2) {
    for (int e = tid; e < 4096; e += 256) {
      int st = e >> 7, r = (e >> 2) & 31, slot = e & 3;
      long g = (long)r * wrs + st * 32 + slot * 8;
      int o = st * 2048 + r * 64 + ((slot ^ (r & 3)) << 4);
      *(u32x4*)(W_HI + o) = *(const u32x4*)(Wg_h + g);
      *(u32x4*)(W_LO + o) = *(const u32x4*)(Wg_l + g);
    }
  }
  __syncthreads();

  float hpv = memory[sb * 1024 + sq * 256 + tid];

  for (int t = 0; t < T_; ++t) {
    // ========== Ph1: gates GEMMs (blocks 0..191, direct-A, no barriers) =====
    if (isGI || isGH) {
      const u16* Ah;
      const u16* Al;
      float* outp;
      if (isGI) {
        Ah = dctx_h + (long)t * 65536 + kc * 512;   // rotation-fresh
        Al = dctx_l + (long)t * 65536 + kc * 512;
        outp = gip + (long)kc * 196608 + nt * 64;
      } else {
        Ah = hh_r + (long)t * 65536 + kc * 512;
        Al = hl_r + (long)t * 65536 + kc * 512;
        outp = ghp + (long)kc * 196608 + nt * 64;
      }
      f32x4 acc[2][2];
#pragma unroll
      for (int i = 0; i < 2; ++i)
#pragma unroll
        for (int j = 0; j < 2; ++j) acc[i][j] = z4;
      gemm_dir<2, 16>(Ah, Al, W_HI, W_LO, wm, wn, l15, kq, acc);
#pragma unroll
      for (int mi = 0; mi < 2; ++mi)
#pragma unroll
        for (int ni = 0; ni < 2; ++ni)
#pragma unroll
          for (int e = 0; e < 4; ++e) {
            int r = (wm << 5) + (mi << 4) + (kq << 2) + e;
            int c = (wn << 5) + (ni << 4) + l15;
            astore_f32(outp + (long)r * 3072 + c, acc[mi][ni][e]);
          }
    }
    gridbar(flags, seq); seq++;

    // ========== Ph2a: GRU quarter + partial scores (ALL 256 blocks) ========
    {
      const int b = sb, q = sq;
      const int j = (q << 8) + tid;
      const float* eb = embi + ((long)t * 64 + b) * 3072;
      float g0r = __uint_as_float(aload_u32(gip + b * 3072 + j));
      float g1r = __uint_as_float(aload_u32(gip + 196608 + b * 3072 + j));
      float g0z = __uint_as_float(aload_u32(gip + b * 3072 + 1024 + j));
      float g1z = __uint_as_float(aload_u32(gip + 196608 + b * 3072 + 1024 + j));
      float g0n = __uint_as_float(aload_u32(gip + b * 3072 + 2048 + j));
      float g1n = __uint_as_float(aload_u32(gip + 196608 + b * 3072 + 2048 + j));
      float h0r = __uint_as_float(aload_u32(ghp + b * 3072 + j));
      float h1r = __uint_as_float(aload_u32(ghp + 196608 + b * 3072 + j));
      float h0z = __uint_as_float(aload_u32(ghp + b * 3072 + 1024 + j));
      float h1z = __uint_as_float(aload_u32(ghp + 196608 + b * 3072 + 1024 + j));
      float h0n = __uint_as_float(aload_u32(ghp + b * 3072 + 2048 + j));
      float h1n = __uint_as_float(aload_u32(ghp + 196608 + b * 3072 + 2048 + j));
      float ir = eb[j] + g0r + g1r + bih[j];
      float iz = eb[1024 + j] + g0z + g1z + bih[1024 + j];
      float in2 = eb[2048 + j] + g0n + g1n + bih[2048 + j];
      float hr = h0r + h1r + bhh[j];
      float hz = h0z + h1z + bhh[1024 + j];
      float hn = h0n + h1n + bhh[2048 + j];
      float r = 1.f / (1.f + expf(-(ir + hr)));
      float z = 1.f / (1.f + expf(-(iz + hz)));
      float n = tanhf(in2 + r * hn);
      float h = (1.f - z) * n + z * hpv;
      hpv = h;
      hq[tid] = h;
      if (t == T_ - 1) dout[HID_OFF + (long)b * 1024 + j] = h;
      __syncthreads();
      if (tid < 64) {
        u64 ph = 0, pl = 0;
#pragma unroll
        for (int ii = 0; ii < 4; ++ii) {
          u16 hi, lo;
          split2(hq[tid * 4 + ii], &hi, &lo);
          ph |= (u64)hi << (16 * ii);
          pl |= (u64)lo << (16 * ii);
        }
        long o = (long)(t + 1) * 65536 + (long)b * 1024 + (q << 8) + tid * 4;
        astore_u64(hh_r + o, ph);
        astore_u64(hl_r + o, pl);
      }
      {
        int s = tid >> 2, part = tid & 3;
        const float4* ep = (const float4*)(encT + (((long)b * 64 + s) << 10) + (q << 8) + (part << 6));
        const float4* hp = (const float4*)(hq + (part << 6));
        float dot = 0.f;
#pragma unroll
        for (int kk = 0; kk < 16; ++kk) {
          float4 e = ep[kk], a = hp[kk];
          dot += e.x * a.x + e.y * a.y + e.z * a.z + e.w * a.w;
        }
        dot += __shfl_xor(dot, 1);
        dot += __shfl_xor(dot, 2);
        if (part == 0) astore_f32(psc + (((b << 2) + q) << 6) + s, dot);
      }
    }
    gridbar(flags, seq); seq++;

    // ========== Ph2c: softmax (redundant) + partial ctx (ALL blocks) =======
    {
      const int b = sb, q = sq;
      if (tid < 64) {
        int s = tid;
        float v = 0.f;
#pragma unroll
        for (int qq = 0; qq < 4; ++qq)
          v += __uint_as_float(aload_u32(psc + (((b << 2) + qq) << 6) + s));
        int len = xs_len[b];
        if (s >= len || v == 0.0f) v = -1e10f;
        float m = v;
#pragma unroll
        for (int off = 32; off; off >>= 1) m = fmaxf(m, __shfl_xor(m, off));
        float p = expf(v - m);
        float sum = p;
#pragma unroll
        for (int off = 32; off; off >>= 1) sum += __shfl_xor(sum, off);
        float a = p / sum;
        at_s[s] = a;
        if (q == 0) dout[ATT_OFF + ((long)b * T_ + t) * S_ + s] = a;
      }
      __syncthreads();
      {
        const float* lp = encL + (((long)b * 64 + (q << 4)) << 10) + tid * 4;
        float c0 = 0.f, c1 = 0.f, c2 = 0.f, c3 = 0.f;
#pragma unroll
        for (int s2 = 0; s2 < 16; ++s2) {
          float a = at_s[(q << 4) + s2];
          float4 e = *(const float4*)(lp + (s2 << 10));
          c0 += a * e.x; c1 += a * e.y; c2 += a * e.z; c3 += a * e.w;
        }
        u64 w0 = ((u64)__float_as_uint(c1) << 32) | __float_as_uint(c0);
        u64 w1 = ((u64)__float_as_uint(c3) << 32) | __float_as_uint(c2);
        long o = (((long)(b << 2) + q) << 10) + tid * 4;
        astore_u64(ctxp + o, w0);
        astore_u64(ctxp + o + 2, w1);
      }
    }
    gridbar(flags, seq); seq++;

    // ========== Ph3: dctx[t+1] (blocks 192..223, direct-A, no barriers) =====
    if (isL2) {
      f32x4 acc1[2][1];
      acc1[0][0] = z4; acc1[1][0] = z4;
      gemm_dir<1, 32>(hh_r + (long)(t + 1) * 65536, hl_r + (long)(t + 1) * 65536,
                      W_HI, W_LO, wm, wn, l15, kq, acc1);
      __syncthreads();
      float* cf = (float*)(L + 131072);  // 64x32 f32 = 8 KB
#pragma unroll
      for (int mi = 0; mi < 2; ++mi)
#pragma unroll
        for (int e = 0; e < 4; ++e) {
          int rr = (wm << 5) + (mi << 4) + (kq << 2) + e;
          int cc = (wn << 4) + l15;
          float a = 0.f;
#pragma unroll
          for (int qq = 0; qq < 4; ++qq)
            a += __uint_as_float(aload_u32(ctxp + (((long)(rr << 2) + qq) << 10) + n0 + cc));
          float v = tanhf(acc1[mi][0][e] + a);
          if (t == T_ - 1) dout[CTF_OFF + (long)rr * 1024 + n0 + cc] = v;
          cf[rr * 32 + cc] = v;
        }
      __syncthreads();
#pragma unroll
      for (int qq2 = 0; qq2 < 2; ++qq2) {
        int g = tid + qq2 * 256;
        int b = g >> 3, colg = g & 7;
        u64 ph = 0, pl = 0;
#pragma unroll
        for (int ii = 0; ii < 4; ++ii) {
          float v = cf[b * 32 + colg * 4 + ii];
          u16 hi, lo;
          split2(v, &hi, &lo);
          ph |= (u64)hi << (16 * ii);
          pl |= (u64)lo << (16 * ii);
        }
        long o = (long)(t + 1) * 65536 + (long)b * 1024 + n0 + colg * 4;
        astore_u64(dctx_h + o, ph);
        astore_u64(dctx_l + o, pl);
      }
    }
    if (t < T_ - 1) { gridbar(flags, seq); }
    seq++;
  }
}

// ---------------- log-softmax: combine partials + subtract pass ----------------
__launch_bounds__(256)
__global__ void k_lsm(float* __restrict__ dout, const float2* __restrict__ psum) {
  int R = blockIdx.x;
  long base = (long)R * V_;
  int gm = ((R & 31) << 6) + (R >> 5);
  const float2* pp = psum + ((long)gm << 8);
  int tid = threadIdx.x;
  float m = -3.0e38f, s = 0.f;
  if (tid < 250) {
    float2 p = pp[tid];
    m = p.x;
    s = p.y;
  }
#pragma unroll
  for (int off = 32; off; off >>= 1) {
    float mo = __shfl_xor(m, off), so = __shfl_xor(s, off);
    lse_comb(m, s, mo, so);
  }
  __shared__ float ms[4], ss[4];
  if ((tid & 63) == 0) { ms[tid >> 6] = m; ss[tid >> 6] = s; }
  __syncthreads();
  float M = ms[0], S = ss[0];
  for (int w2 = 1; w2 < 4; ++w2) lse_comb(M, S, ms[w2], ss[w2]);
  float logden = M + logf(S);
  float4* q4 = (float4*)(dout + base);
#pragma unroll 4
  for (int it = 0; it < 31; ++it) {
    float4 x = q4[it * 256 + tid];
    x.x -= logden; x.y -= logden; x.z -= logden; x.w -= logden;
    q4[it * 256 + tid] = x;
  }
  if (tid < 64) {
    float4 x = q4[7936 + tid];
    x.x -= logden; x.y -= logden; x.z -= logden; x.w -= logden;
    q4[7936 + tid] = x;
  }
}

// ---------------- host launcher ----------------
extern "C" void kernel_launch(void* const* d_in, const int* in_sizes, int n_in,
                              void* d_out, int out_size, void* d_ws, size_t ws_size,
                              hipStream_t stream) {
  (void)in_sizes; (void)n_in; (void)out_size;
  const int* input = (const int*)d_in[0];
  const float* memory = (const float*)d_in[1];
  const float* enc = (const float*)d_in[2];
  const int* xs_len = (const int*)d_in[3];
  const float* emb = (const float*)d_in[4];
  const float* wih = (const float*)d_in[5];
  const float* whh = (const float*)d_in[6];
  const float* bih = (const float*)d_in[7];
  const float* bhh = (const float*)d_in[8];
  const float* l1 = (const float*)d_in[9];
  const float* l2 = (const float*)d_in[10];
  const float* wout = (const float*)d_in[11];
  const float* bout = (const float*)d_in[12];
  float* out = (float*)d_out;
  char* w = (char*)d_ws;

  size_t off = 0;
  auto alloc = [&](size_t bytes) {
    size_t o = off;
    off = (off + bytes + 255) & ~(size_t)255;
    return o;
  };
  const size_t N_WIH = 3072UL * 2048, N_WHH = 3072UL * 1024, N_L2 = 1024UL * 2048;
  const size_t N_L1 = 1024UL * 1024, N_ENC = 4096UL * 1024, N_WOUT = 32000UL * 1024;
  const size_t N_EMBX = 2048UL * 1024, N_ENCT = 4096UL * 1024;
  const size_t N_EMBI = 2048UL * 3072, N_ROT = 33UL * 65536;

  size_t o_wih_h = alloc(2 * N_WIH), o_wih_l = alloc(2 * N_WIH);
  size_t o_whh_h = alloc(2 * N_WHH), o_whh_l = alloc(2 * N_WHH);
  size_t o_l2_h = alloc(2 * N_L2), o_l2_l = alloc(2 * N_L2);
  size_t o_l1t_h = alloc(2 * N_L1), o_l1t_l = alloc(2 * N_L1);
  size_t o_ctx_h = alloc(2 * N_ROT), o_ctx_l = alloc(2 * N_ROT);
  size_t o_hh = alloc(2 * N_ROT), o_hl = alloc(2 * N_ROT);
  size_t o_gip = alloc(4 * 2 * 196608), o_ghp = alloc(4 * 2 * 196608);
  size_t o_psc = alloc(4 * 16384);
  size_t o_ctxp = alloc(4 * 262144);
  size_t o_psum = alloc(8UL * 2048 * 256);
  size_t o_bar = alloc(16384);
  size_t o_arena = alloc(2 * N_ENC * 2 + 2 * N_EMBX * 2 + 4 * N_EMBI + 4 * N_ENCT * 2);

  if (off > ws_size) {
    k_guard<<<1, 1, 0, stream>>>(out, 1.0e8f + (float)(ws_size >> 20));
    return;
  }

  u16* wih_h = (u16*)(w + o_wih_h);   u16* wih_l = (u16*)(w + o_wih_l);
  u16* whh_h = (u16*)(w + o_whh_h);   u16* whh_l = (u16*)(w + o_whh_l);
  u16* l2_h = (u16*)(w + o_l2_h);     u16* l2_l = (u16*)(w + o_l2_l);
  u16* l1t_h = (u16*)(w + o_l1t_h);   u16* l1t_l = (u16*)(w + o_l1t_l);
  u16* ctx_h = (u16*)(w + o_ctx_h);   u16* ctx_l = (u16*)(w + o_ctx_l);
  u16* hh_r = (u16*)(w + o_hh);       u16* hl_r = (u16*)(w + o_hl);
  float* gip = (float*)(w + o_gip);
  float* ghp = (float*)(w + o_ghp);
  float* psc = (float*)(w + o_psc);
  float* ctxp = (float*)(w + o_ctxp);
  float2* psum = (float2*)(w + o_psum);
  unsigned* flags = (unsigned*)(w + o_bar);

  char* ar = w + o_arena;
  u16* enc_h = (u16*)ar;
  u16* enc_l = (u16*)(ar + 2 * N_ENC);
  u16* embx_h = (u16*)(ar + 4 * N_ENC);
  u16* embx_l = (u16*)(ar + 4 * N_ENC + 2 * N_EMBX);
  float* embi = (float*)(ar + 4 * N_ENC + 4 * N_EMBX);
  float* encT = (float*)(ar + 4 * N_ENC + 4 * N_EMBX + 4 * N_EMBI);
  float* encL = (float*)(ar + 4 * N_ENC + 4 * N_EMBX + 4 * N_EMBI + 4 * N_ENCT);
  u16* wout_b = (u16*)ar;  // overlays prep arena after k_rec

  hipFuncSetAttribute((const void*)k_rec, hipFuncAttributeMaxDynamicSharedMemorySize,
                      LDS_BYTES);

  // prep (fused splits)
  k_split4<<<4096, 256, 0, stream>>>(wih, wih_h, wih_l, (int)N_WIH,
                                     whh, whh_h, whh_l, (int)N_WHH,
                                     l2, l2_h, l2_l, (int)N_L2,
                                     enc, enc_h, enc_l, (int)N_ENC);
  k_l1t<<<256, 256, 0, stream>>>(l1, l1t_h, l1t_l);
  k_embx<<<2048, 256, 0, stream>>>(input, emb, embx_h, embx_l);
  k_h0<<<256, 256, 0, stream>>>(memory, hh_r, hl_r);
  hipMemsetAsync(ctx_h, 0, 131072, stream);
  hipMemsetAsync(ctx_l, 0, 131072, stream);
  hipMemsetAsync(flags, 0, 16384, stream);

  // encT = enc @ l1 ; encL = enc @ l2a^T ; embi = embx @ w_ih[:, :1024]^T
  k_gemmG<<<256, 256, 0, stream>>>(enc_h, enc_l, l1t_h, l1t_l, encT,
                                   32, 1024, 1024, 1024);
  k_gemmG<<<256, 256, 0, stream>>>(enc_h, enc_l, l2_h, l2_l, encL,
                                   32, 1024, 2048, 1024);
  k_gemmG<<<384, 256, 0, stream>>>(embx_h, embx_l, wih_h, wih_l, embi,
                                   16, 1024, 2048, 3072);

  // persistent recurrence (direct-A GEMMs)
  k_rec<<<NB_, 256, LDS_BYTES, stream>>>(embi, ctx_h, ctx_l, hh_r, hl_r, memory,
                                         wih_h, wih_l, whh_h, whh_l, l2_h, l2_l,
                                         gip, ghp, psc, ctxp, encT, encL,
                                         xs_len, bih, bhh, out, flags);

  // wout -> bf16 (overlays dead prep arena)
  k_tobf<<<4096, 256, 0, stream>>>(wout, wout_b, (int)N_WOUT);

  // logits GEMM (gll16 staging, XCD-contiguous nt) + partial LSE
  k_gemmL<<<4000, 256, 0, stream>>>(ctx_h + 65536, wout_b, bout, out, psum);

  // log-softmax: combine partials, subtract in place
  k_lsm<<<2048, 256, 0, stream>>>(out, psum);
}

// Round 15
// 2074.214 us; speedup vs baseline: 1.0802x; 1.0802x over previous
//
#include <hip/hip_runtime.h>

// ---------------------------------------------------------------------------
// AttentionDecoder: B=64 T=32 S=64 H=1024 V=32000
// R15: R14 with the deadlock fixed: cdone moved to flags+4090 (R14 had it at
//      flags+4000 == block 250's barrier flag word -> counter clobbered ->
//      Ph3 polled forever). Everything else identical to R14:
//  - 3 grid barriers/step. Blocks 192..223 run l2b GEMM right after bar2;
//    other blocks run Ph2c jobs + release-add cdone; Ph3 polls cdone AFTER
//    its GEMM mainloop, then reads ctxp in the epilogue.
//  - Job map: jobs 0..191 -> blocks 0..191; 192..223 -> blocks 224..255;
//    224..255 -> blocks 0..31 (second job).
// ---------------------------------------------------------------------------

#define B_ 64
#define T_ 32
#define S_ 64
#define H_ 1024
#define V_ 32000
#define NB_ 256
#define LDS_BYTES 152064

#define HID_OFF 65536000L
#define ATT_OFF 65601536L
#define CTF_OFF 65732608L

typedef __attribute__((ext_vector_type(8))) short bf16x8;
typedef __attribute__((ext_vector_type(4))) float f32x4;
typedef __attribute__((ext_vector_type(4))) unsigned int u32x4;
typedef unsigned short u16;
typedef unsigned long long u64;

__device__ __forceinline__ u16 f2bf(float v) {
  unsigned int u = __float_as_uint(v);
  unsigned int r = (u + 0x7fffu + ((u >> 16) & 1u)) >> 16;  // RNE
  return (u16)r;
}
__device__ __forceinline__ float bf2f(u16 h) {
  return __uint_as_float(((unsigned int)h) << 16);
}
__device__ __forceinline__ void split2(float v, u16* hi, u16* lo) {
  u16 h = f2bf(v);
  *hi = h;
  *lo = f2bf(v - bf2f(h));
}

// ---- coherent-path (agent-scope relaxed atomic) helpers ----
__device__ __forceinline__ u64 aload_u64(const void* p) {
  return __hip_atomic_load((const u64*)p, __ATOMIC_RELAXED, __HIP_MEMORY_SCOPE_AGENT);
}
__device__ __forceinline__ unsigned aload_u32(const void* p) {
  return __hip_atomic_load((const unsigned*)p, __ATOMIC_RELAXED, __HIP_MEMORY_SCOPE_AGENT);
}
__device__ __forceinline__ void astore_u64(void* p, u64 v) {
  __hip_atomic_store((u64*)p, v, __ATOMIC_RELAXED, __HIP_MEMORY_SCOPE_AGENT);
}
__device__ __forceinline__ void astore_f32(float* p, float v) {
  __hip_atomic_store((unsigned*)p, __float_as_uint(v), __ATOMIC_RELAXED,
                     __HIP_MEMORY_SCOPE_AGENT);
}

// ---- async global->LDS (16B/lane) ----
__device__ __forceinline__ void gll16(const u16* g, u16* l) {
  __builtin_amdgcn_global_load_lds(
      (const __attribute__((address_space(1))) void*)g,
      (__attribute__((address_space(3))) void*)l, 16, 0, 0);
}

// ---------------- conversion / prep kernels ----------------

__global__ void k_split4(const float* __restrict__ sA, u16* __restrict__ hA,
                         u16* __restrict__ lA, int nA,
                         const float* __restrict__ sB, u16* __restrict__ hB,
                         u16* __restrict__ lB, int nB,
                         const float* __restrict__ sC, u16* __restrict__ hC,
                         u16* __restrict__ lC, int nC,
                         const float* __restrict__ sD, u16* __restrict__ hD,
                         u16* __restrict__ lD, int nD) {
  int i = blockIdx.x * blockDim.x + threadIdx.x;
  int stride = gridDim.x * blockDim.x;
  int t1 = nA, t2 = nA + nB, t3 = t2 + nC, total = t3 + nD;
  for (; i < total; i += stride) {
    if (i < t1) split2(sA[i], &hA[i], &lA[i]);
    else if (i < t2) { int j = i - t1; split2(sB[j], &hB[j], &lB[j]); }
    else if (i < t3) { int j = i - t2; split2(sC[j], &hC[j], &lC[j]); }
    else { int j = i - t3; split2(sD[j], &hD[j], &lD[j]); }
  }
}

__global__ void k_tobf(const float* __restrict__ src, u16* __restrict__ dst, int n) {
  int i = blockIdx.x * blockDim.x + threadIdx.x;
  int stride = gridDim.x * blockDim.x;
  for (; i < n; i += stride) dst[i] = f2bf(src[i]);
}

// l1 (H,H) row-major [i][k] -> l1T hi/lo [k][i]
__global__ void k_l1t(const float* __restrict__ l1, u16* __restrict__ hi,
                      u16* __restrict__ lo) {
  __shared__ float tile[64][65];
  int it = blockIdx.x & 15, kt = blockIdx.x >> 4;
  for (int q = 0; q < 16; ++q) {
    int idx = q * 256 + threadIdx.x;
    int r = idx >> 6, c = idx & 63;
    tile[r][c] = l1[(long)(it * 64 + r) * H_ + kt * 64 + c];
  }
  __syncthreads();
  for (int q = 0; q < 16; ++q) {
    int idx = q * 256 + threadIdx.x;
    int r = idx >> 6, c = idx & 63;
    long o = (long)(kt * 64 + r) * H_ + it * 64 + c;
    split2(tile[c][r], &hi[o], &lo[o]);
  }
}

// gather embeddings: embx[t][b][k] hi/lo
__global__ void k_embx(const int* __restrict__ inp, const float* __restrict__ emb,
                       u16* __restrict__ hi, u16* __restrict__ lo) {
  int bt = blockIdx.x;
  int b = bt >> 5, t = bt & 31;
  int id = inp[b * T_ + t];
  const float* src = emb + (long)id * H_;
  long base = (long)(t * B_ + b) * H_;
  for (int k = threadIdx.x; k < H_; k += 256) split2(src[k], &hi[base + k], &lo[base + k]);
}

// h0 -> hh_r/hl_r slot 0
__global__ void k_h0(const float* __restrict__ mem, u16* __restrict__ hh,
                     u16* __restrict__ hl) {
  int i = blockIdx.x * 256 + threadIdx.x;  // 65536
  float v = mem[i];
  split2(v, &hh[i], &hl[i]);
}

__global__ void k_guard(float* out, float v) {
  if (blockIdx.x == 0 && threadIdx.x == 0) out[0] = v;
}

// ------- prep GEMM: 128x128 tile, K=1024, split-bf16, gll16 staging -------
__launch_bounds__(256)
__global__ void k_gemmG(const u16* __restrict__ Ah, const u16* __restrict__ Al,
                        const u16* __restrict__ Bh, const u16* __restrict__ Bl,
                        float* __restrict__ C, int Mtiles, int Arow, int Brow,
                        int Crow) {
  int bx = blockIdx.x;
  int mt = bx % Mtiles, nt = bx / Mtiles;
  int m0 = mt << 7, n0 = nt << 7;

  __shared__ __attribute__((aligned(16))) u16 lds[4 * 4096];  // 32 KB
  char* L = (char*)lds;
  const int tid = threadIdx.x;
  const int lane = tid & 63, wid = tid >> 6;
  const int wm = wid & 1, wn = wid >> 1;
  const int l15 = lane & 15, kq = lane >> 4;

  const int r8 = lane >> 2, ss = lane & 3;
  const int rA0 = (wid << 4) + r8, rA1 = rA0 + 64;
  const int sw0 = (ss ^ (rA0 & 3)) << 3, sw1 = (ss ^ (rA1 & 3)) << 3;
  const u16* gAh0 = Ah + (long)(m0 + rA0) * Arow + sw0;
  const u16* gAh1 = Ah + (long)(m0 + rA1) * Arow + sw1;
  const u16* gAl0 = Al + (long)(m0 + rA0) * Arow + sw0;
  const u16* gAl1 = Al + (long)(m0 + rA1) * Arow + sw1;
  const u16* gBh0 = Bh + (long)(n0 + rA0) * Brow + sw0;
  const u16* gBh1 = Bh + (long)(n0 + rA1) * Brow + sw1;
  const u16* gBl0 = Bl + (long)(n0 + rA0) * Brow + sw0;
  const u16* gBl1 = Bl + (long)(n0 + rA1) * Brow + sw1;
  u16* dAh0 = (u16*)(L + (wid << 10));
  u16* dAh1 = (u16*)(L + 4096 + (wid << 10));
  u16* dBh0 = (u16*)(L + 8192 + (wid << 10));
  u16* dBh1 = (u16*)(L + 12288 + (wid << 10));
  u16* dAl0 = (u16*)(L + 16384 + (wid << 10));
  u16* dAl1 = (u16*)(L + 20480 + (wid << 10));
  u16* dBl0 = (u16*)(L + 24576 + (wid << 10));
  u16* dBl1 = (u16*)(L + 28672 + (wid << 10));

  f32x4 acc[4][4];
  const f32x4 z4 = {0.f, 0.f, 0.f, 0.f};
#pragma unroll
  for (int i = 0; i < 4; ++i)
#pragma unroll
    for (int j = 0; j < 4; ++j) acc[i][j] = z4;

  for (int kt = 0; kt < 32; ++kt) {
    __syncthreads();
    int ko = kt << 5;
    gll16(gAh0 + ko, dAh0);
    gll16(gAh1 + ko, dAh1);
    gll16(gBh0 + ko, dBh0);
    gll16(gBh1 + ko, dBh1);
    gll16(gAl0 + ko, dAl0);
    gll16(gAl1 + ko, dAl1);
    gll16(gBl0 + ko, dBl0);
    gll16(gBl1 + ko, dBl1);
    __syncthreads();
    bf16x8 aH[4], bH[4], aL[4], bL[4];
#pragma unroll
    for (int mi = 0; mi < 4; ++mi) {
      int r = (wm << 6) + (mi << 4) + l15;
      int off = r * 64 + ((kq ^ (r & 3)) << 4);
      aH[mi] = *(const bf16x8*)(L + off);
      aL[mi] = *(const bf16x8*)(L + 16384 + off);
    }
#pragma unroll
    for (int ni = 0; ni < 4; ++ni) {
      int c = (wn << 6) + (ni << 4) + l15;
      int off = c * 64 + ((kq ^ (c & 3)) << 4);
      bH[ni] = *(const bf16x8*)(L + 8192 + off);
      bL[ni] = *(const bf16x8*)(L + 24576 + off);
    }
#pragma unroll
    for (int mi = 0; mi < 4; ++mi)
#pragma unroll
      for (int ni = 0; ni < 4; ++ni) {
        acc[mi][ni] = __builtin_amdgcn_mfma_f32_16x16x32_bf16(aH[mi], bH[ni], acc[mi][ni], 0, 0, 0);
        acc[mi][ni] = __builtin_amdgcn_mfma_f32_16x16x32_bf16(aL[mi], bH[ni], acc[mi][ni], 0, 0, 0);
        acc[mi][ni] = __builtin_amdgcn_mfma_f32_16x16x32_bf16(aH[mi], bL[ni], acc[mi][ni], 0, 0, 0);
      }
  }
#pragma unroll
  for (int mi = 0; mi < 4; ++mi)
#pragma unroll
    for (int ni = 0; ni < 4; ++ni)
#pragma unroll
      for (int e = 0; e < 4; ++e) {
        int r = (wm << 6) + (mi << 4) + (kq << 2) + e;
        int c = (wn << 6) + (ni << 4) + l15;
        C[(long)(m0 + r) * Crow + n0 + c] = acc[mi][ni][e];
      }
}

__device__ __forceinline__ void lse_comb(float& m, float& s, float mo, float so) {
  float M = fmaxf(m, mo);
  s = s * __expf(m - M) + so * __expf(mo - M);
  m = M;
}

// ---------------- logits GEMM + partial-LSE epilogue ----------------
__launch_bounds__(256)
__global__ void k_gemmL(const u16* __restrict__ A, const u16* __restrict__ Bw,
                        const float* __restrict__ bias, float* __restrict__ C,
                        float2* __restrict__ psum) {
  int bx = blockIdx.x;
  int wg = (bx & 7) * 500 + (bx >> 3);  // XCD-contiguous
  int mt = wg & 15, nt = wg >> 4;
  int m0 = mt << 7, n0 = nt << 7;

  __shared__ __attribute__((aligned(16))) u16 lds[2 * 4096];  // 16 KB
  __shared__ float2 lsep[128][2];
  char* L = (char*)lds;
  const int tid = threadIdx.x;
  const int lane = tid & 63, wid = tid >> 6;
  const int wm = wid & 1, wn = wid >> 1;
  const int l15 = lane & 15, kq = lane >> 4;

  const int r8 = lane >> 2, ss = lane & 3;
  const int rA0 = (wid << 4) + r8, rA1 = rA0 + 64;
  const u16* gA0 = A + (long)(m0 + rA0) * 1024 + ((ss ^ (rA0 & 3)) << 3);
  const u16* gA1 = A + (long)(m0 + rA1) * 1024 + ((ss ^ (rA1 & 3)) << 3);
  const u16* gB0 = Bw + (long)(n0 + rA0) * 1024 + ((ss ^ (rA0 & 3)) << 3);
  const u16* gB1 = Bw + (long)(n0 + rA1) * 1024 + ((ss ^ (rA1 & 3)) << 3);
  u16* lA0 = (u16*)(L + (wid << 10));
  u16* lA1 = (u16*)(L + 4096 + (wid << 10));
  u16* lB0 = (u16*)(L + 8192 + (wid << 10));
  u16* lB1 = (u16*)(L + 12288 + (wid << 10));

  f32x4 acc[4][4];
  const f32x4 z4 = {0.f, 0.f, 0.f, 0.f};
#pragma unroll
  for (int i = 0; i < 4; ++i)
#pragma unroll
    for (int j = 0; j < 4; ++j) acc[i][j] = z4;

  for (int kt = 0; kt < 32; ++kt) {
    __syncthreads();
    gll16(gA0 + (kt << 5), lA0);
    gll16(gA1 + (kt << 5), lA1);
    gll16(gB0 + (kt << 5), lB0);
    gll16(gB1 + (kt << 5), lB1);
    __syncthreads();
    bf16x8 aF[4], bF[4];
#pragma unroll
    for (int mi = 0; mi < 4; ++mi) {
      int r = (wm << 6) + (mi << 4) + l15;
      aF[mi] = *(const bf16x8*)(L + r * 64 + ((kq ^ (r & 3)) << 4));
    }
#pragma unroll
    for (int ni = 0; ni < 4; ++ni) {
      int c = (wn << 6) + (ni << 4) + l15;
      bF[ni] = *(const bf16x8*)(L + 8192 + c * 64 + ((kq ^ (c & 3)) << 4));
    }
#pragma unroll
    for (int mi = 0; mi < 4; ++mi)
#pragma unroll
      for (int ni = 0; ni < 4; ++ni)
        acc[mi][ni] = __builtin_amdgcn_mfma_f32_16x16x32_bf16(aF[mi], bF[ni], acc[mi][ni], 0, 0, 0);
  }
  float b4[4];
#pragma unroll
  for (int ni = 0; ni < 4; ++ni) b4[ni] = bias[n0 + (wn << 6) + (ni << 4) + l15];
#pragma unroll
  for (int mi = 0; mi < 4; ++mi)
#pragma unroll
    for (int e = 0; e < 4; ++e) {
      int r = (wm << 6) + (mi << 4) + (kq << 2) + e;
      int gm = m0 + r;
      float vv[4], vm = -3.0e38f, vs = 0.f;
#pragma unroll
      for (int ni = 0; ni < 4; ++ni) {
        vv[ni] = acc[mi][ni][e] + b4[ni];
        vm = fmaxf(vm, vv[ni]);
      }
#pragma unroll
      for (int ni = 0; ni < 4; ++ni) {
        vs += __expf(vv[ni] - vm);
        int gn = n0 + (wn << 6) + (ni << 4) + l15;
        C[((long)(gm & 63) * T_ + (gm >> 6)) * V_ + gn] = vv[ni];
      }
#pragma unroll
      for (int o = 1; o < 16; o <<= 1) {
        float mo = __shfl_xor(vm, o), so = __shfl_xor(vs, o);
        lse_comb(vm, vs, mo, so);
      }
      if (l15 == 0) lsep[r][wn] = make_float2(vm, vs);
    }
  __syncthreads();
  if (tid < 128) {
    float2 a = lsep[tid][0], b2 = lsep[tid][1];
    float M = a.x, S = a.y;
    lse_comb(M, S, b2.x, b2.y);
    psum[((long)(m0 + tid) << 8) + nt] = make_float2(M, S);
  }
}

// ---------------- grid barrier (R7 verbatim) ----------------
__device__ __forceinline__ void gridbar(unsigned* flags, unsigned seq) {
  __syncthreads();
  if (threadIdx.x == 0)
    __hip_atomic_store(flags + blockIdx.x * 16, seq, __ATOMIC_RELEASE,
                       __HIP_MEMORY_SCOPE_AGENT);
  if (threadIdx.x < 64) {
    int l = threadIdx.x;
    for (;;) {
      unsigned a = __hip_atomic_load(flags + l * 16, __ATOMIC_RELAXED, __HIP_MEMORY_SCOPE_AGENT);
      unsigned b = __hip_atomic_load(flags + (l + 64) * 16, __ATOMIC_RELAXED, __HIP_MEMORY_SCOPE_AGENT);
      unsigned c = __hip_atomic_load(flags + (l + 128) * 16, __ATOMIC_RELAXED, __HIP_MEMORY_SCOPE_AGENT);
      unsigned d = __hip_atomic_load(flags + (l + 192) * 16, __ATOMIC_RELAXED, __HIP_MEMORY_SCOPE_AGENT);
      if (__all((a >= seq) & (b >= seq) & (c >= seq) & (d >= seq))) break;
      __builtin_amdgcn_s_sleep(1);
    }
  }
  __syncthreads();
}

// ---------------- persistent recurrence kernel ----------------
__launch_bounds__(256)
__global__ void k_rec(const float* __restrict__ embi,
                      u16* __restrict__ dctx_h, u16* __restrict__ dctx_l,
                      u16* __restrict__ hh_r, u16* __restrict__ hl_r,
                      const float* __restrict__ memory,
                      const u16* __restrict__ wih_h, const u16* __restrict__ wih_l,
                      const u16* __restrict__ whh_h, const u16* __restrict__ whh_l,
                      const u16* __restrict__ l2_h, const u16* __restrict__ l2_l,
                      float* __restrict__ gip, float* __restrict__ ghp,
                      float* __restrict__ psc, float* __restrict__ ctxp,
                      const float* __restrict__ encT, const float* __restrict__ encL,
                      const int* __restrict__ xs_len,
                      const float* __restrict__ bih, const float* __restrict__ bhh,
                      float* __restrict__ dout, unsigned* flags) {
  extern __shared__ __attribute__((aligned(16))) char L[];
  char* W_HI = L;
  char* W_LO = L + 65536;
  char* A_HI = L + 131072;
  char* A_LO = L + 139264;
  float* hq = (float*)(L + 147456);
  float* at_s = (float*)(L + 148480);
  unsigned* cdone = flags + 4090;  // FIX: outside barrier flag range (0..4080)
  const int bx = blockIdx.x;
  const int tid = threadIdx.x;
  const int lane = tid & 63, wid = tid >> 6;
  const int wm = wid & 1, wn = wid >> 1;
  const int l15 = lane & 15, kq = lane >> 4;
  const f32x4 z4 = {0.f, 0.f, 0.f, 0.f};
  unsigned seq = 1;

  const int isGI = (bx < 96);
  const int isGH = (bx >= 96 && bx < 192);
  const int isL2 = (bx >= 192 && bx < 224);
  const int sb = bx >> 2;
  const int sq = bx & 3;
  int nt = 0, kc = 0, n0 = 0;
  const u16 *Wg_h = nullptr, *Wg_l = nullptr;
  int wrs = 0;
  if (isGI) {
    nt = bx % 48; kc = bx / 48;
    Wg_h = wih_h + 1024 + (long)nt * 64 * 2048 + kc * 512;
    Wg_l = wih_l + 1024 + (long)nt * 64 * 2048 + kc * 512;
    wrs = 2048;
  } else if (isGH) {
    int j2 = bx - 96;
    nt = j2 % 48; kc = j2 / 48;
    Wg_h = whh_h + (long)nt * 64 * 1024 + kc * 512;
    Wg_l = whh_l + (long)nt * 64 * 1024 + kc * 512;
    wrs = 1024;
  } else if (isL2) {
    n0 = (bx - 192) << 5;
    Wg_h = l2_h + 1024 + (long)n0 * 2048;
    Wg_l = l2_l + 1024 + (long)n0 * 2048;
    wrs = 2048;
  }

  if (isGI || isGH) {
    for (int e = tid; e < 4096; e += 256) {
      int st = e >> 8, r = (e >> 2) & 63, slot = e & 3;
      long g = (long)r * wrs + st * 32 + slot * 8;
      int o = st * 4096 + r * 64 + ((slot ^ (r & 3)) << 4);
      *(u32x4*)(W_HI + o) = *(const u32x4*)(Wg_h + g);
      *(u32x4*)(W_LO + o) = *(const u32x4*)(Wg_l + g);
    }
  } else if (isL2) {
    for (int e = tid; e < 4096; e += 256) {
      int st = e >> 7, r = (e >> 2) & 31, slot = e & 3;
      long g = (long)r * wrs + st * 32 + slot * 8;
      int o = st * 2048 + r * 64 + ((slot ^ (r & 3)) << 4);
      *(u32x4*)(W_HI + o) = *(const u32x4*)(Wg_h + g);
      *(u32x4*)(W_LO + o) = *(const u32x4*)(Wg_l + g);
    }
  }
  __syncthreads();

  float hpv = memory[sb * 1024 + sq * 256 + tid];

  const int pr = tid >> 2, ps = tid & 3;
  const int ao = pr * 64 + ((ps ^ (pr & 3)) << 4);

  for (int t = 0; t < T_; ++t) {
    // ================= Ph1: gates GEMMs (blocks 0..191) =================
    if (isGI || isGH) {
      const u16* Ah;
      const u16* Al;
      float* outp;
      if (isGI) {
        Ah = dctx_h + (long)t * 65536 + kc * 512;
        Al = dctx_l + (long)t * 65536 + kc * 512;
        outp = gip + (long)kc * 196608 + nt * 64;
      } else {
        Ah = hh_r + (long)t * 65536 + kc * 512;
        Al = hl_r + (long)t * 65536 + kc * 512;
        outp = ghp + (long)kc * 196608 + nt * 64;
      }
      const long g0 = (long)pr * 1024 + ps * 8;
      u32x4 ph0 = *(const u32x4*)(Ah + g0);
      u32x4 ph1 = *(const u32x4*)(Ah + g0 + 32);
      u32x4 pl0 = *(const u32x4*)(Al + g0);
      u32x4 pl1 = *(const u32x4*)(Al + g0 + 32);

      f32x4 acc[2][2];
#pragma unroll
      for (int i = 0; i < 2; ++i)
#pragma unroll
        for (int j = 0; j < 2; ++j) acc[i][j] = z4;

      for (int kt = 0; kt < 8; ++kt) {
        __syncthreads();
        *(u32x4*)(A_HI + ao) = ph0;
        *(u32x4*)(A_HI + 4096 + ao) = ph1;
        *(u32x4*)(A_LO + ao) = pl0;
        *(u32x4*)(A_LO + 4096 + ao) = pl1;
        __syncthreads();
        if (kt < 7) {
          long g = g0 + (kt + 1) * 64;
          ph0 = *(const u32x4*)(Ah + g);
          ph1 = *(const u32x4*)(Ah + g + 32);
          pl0 = *(const u32x4*)(Al + g);
          pl1 = *(const u32x4*)(Al + g + 32);
        }
#pragma unroll
        for (int sub = 0; sub < 2; ++sub) {
          const int stw = (kt * 2 + sub) * 4096;
          const int sta = sub * 4096;
          bf16x8 aH[2], aL[2], bH[2], bL[2];
#pragma unroll
          for (int mi = 0; mi < 2; ++mi) {
            int rr = (wm << 5) + (mi << 4) + l15;
            int off = rr * 64 + ((kq ^ (rr & 3)) << 4);
            aH[mi] = *(const bf16x8*)(A_HI + sta + off);
            aL[mi] = *(const bf16x8*)(A_LO + sta + off);
          }
#pragma unroll
          for (int ni = 0; ni < 2; ++ni) {
            int c = (wn << 5) + (ni << 4) + l15;
            int off = c * 64 + ((kq ^ (c & 3)) << 4);
            bH[ni] = *(const bf16x8*)(W_HI + stw + off);
            bL[ni] = *(const bf16x8*)(W_LO + stw + off);
          }
#pragma unroll
          for (int mi = 0; mi < 2; ++mi)
#pragma unroll
            for (int ni = 0; ni < 2; ++ni) {
              acc[mi][ni] = __builtin_amdgcn_mfma_f32_16x16x32_bf16(aH[mi], bH[ni], acc[mi][ni], 0, 0, 0);
              acc[mi][ni] = __builtin_amdgcn_mfma_f32_16x16x32_bf16(aL[mi], bH[ni], acc[mi][ni], 0, 0, 0);
              acc[mi][ni] = __builtin_amdgcn_mfma_f32_16x16x32_bf16(aH[mi], bL[ni], acc[mi][ni], 0, 0, 0);
            }
        }
      }
#pragma unroll
      for (int mi = 0; mi < 2; ++mi)
#pragma unroll
        for (int ni = 0; ni < 2; ++ni)
#pragma unroll
          for (int e = 0; e < 4; ++e) {
            int r = (wm << 5) + (mi << 4) + (kq << 2) + e;
            int c = (wn << 5) + (ni << 4) + l15;
            astore_f32(outp + (long)r * 3072 + c, acc[mi][ni][e]);
          }
    }
    gridbar(flags, seq); seq++;

    // ========== Ph2a: GRU quarter + partial scores (ALL 256 blocks) ========
    {
      const int b = sb, q = sq;
      const int j = (q << 8) + tid;
      const float* eb = embi + ((long)t * 64 + b) * 3072;
      float g0r = __uint_as_float(aload_u32(gip + b * 3072 + j));
      float g1r = __uint_as_float(aload_u32(gip + 196608 + b * 3072 + j));
      float g0z = __uint_as_float(aload_u32(gip + b * 3072 + 1024 + j));
      float g1z = __uint_as_float(aload_u32(gip + 196608 + b * 3072 + 1024 + j));
      float g0n = __uint_as_float(aload_u32(gip + b * 3072 + 2048 + j));
      float g1n = __uint_as_float(aload_u32(gip + 196608 + b * 3072 + 2048 + j));
      float h0r = __uint_as_float(aload_u32(ghp + b * 3072 + j));
      float h1r = __uint_as_float(aload_u32(ghp + 196608 + b * 3072 + j));
      float h0z = __uint_as_float(aload_u32(ghp + b * 3072 + 1024 + j));
      float h1z = __uint_as_float(aload_u32(ghp + 196608 + b * 3072 + 1024 + j));
      float h0n = __uint_as_float(aload_u32(ghp + b * 3072 + 2048 + j));
      float h1n = __uint_as_float(aload_u32(ghp + 196608 + b * 3072 + 2048 + j));
      float ir = eb[j] + g0r + g1r + bih[j];
      float iz = eb[1024 + j] + g0z + g1z + bih[1024 + j];
      float in2 = eb[2048 + j] + g0n + g1n + bih[2048 + j];
      float hr = h0r + h1r + bhh[j];
      float hz = h0z + h1z + bhh[1024 + j];
      float hn = h0n + h1n + bhh[2048 + j];
      float r = 1.f / (1.f + expf(-(ir + hr)));
      float z = 1.f / (1.f + expf(-(iz + hz)));
      float n = tanhf(in2 + r * hn);
      float h = (1.f - z) * n + z * hpv;
      hpv = h;
      hq[tid] = h;
      if (t == T_ - 1) dout[HID_OFF + (long)b * 1024 + j] = h;
      __syncthreads();
      if (tid < 64) {
        u64 ph = 0, pl = 0;
#pragma unroll
        for (int ii = 0; ii < 4; ++ii) {
          u16 hi, lo;
          split2(hq[tid * 4 + ii], &hi, &lo);
          ph |= (u64)hi << (16 * ii);
          pl |= (u64)lo << (16 * ii);
        }
        long o = (long)(t + 1) * 65536 + (long)b * 1024 + (q << 8) + tid * 4;
        astore_u64(hh_r + o, ph);
        astore_u64(hl_r + o, pl);
      }
      {
        int s = tid >> 2, part = tid & 3;
        const float4* ep = (const float4*)(encT + (((long)b * 64 + s) << 10) + (q << 8) + (part << 6));
        const float4* hp = (const float4*)(hq + (part << 6));
        float dot = 0.f;
#pragma unroll
        for (int kk = 0; kk < 16; ++kk) {
          float4 e = ep[kk], a = hp[kk];
          dot += e.x * a.x + e.y * a.y + e.z * a.z + e.w * a.w;
        }
        dot += __shfl_xor(dot, 1);
        dot += __shfl_xor(dot, 2);
        if (part == 0) astore_f32(psc + (((b << 2) + q) << 6) + s, dot);
      }
    }
    gridbar(flags, seq); seq++;

    // ===== Merged phase: Ph3 GEMM (192..223) || Ph2c jobs (others) =====
    if (isL2) {
      const u16* Ah = hh_r + (long)(t + 1) * 65536;
      const u16* Al = hl_r + (long)(t + 1) * 65536;
      const long g0 = (long)pr * 1024 + ps * 8;
      u32x4 ph0 = *(const u32x4*)(Ah + g0);
      u32x4 ph1 = *(const u32x4*)(Ah + g0 + 32);
      u32x4 pl0 = *(const u32x4*)(Al + g0);
      u32x4 pl1 = *(const u32x4*)(Al + g0 + 32);

      f32x4 acc[2];
      acc[0] = z4; acc[1] = z4;
      for (int kt = 0; kt < 16; ++kt) {
        __syncthreads();
        *(u32x4*)(A_HI + ao) = ph0;
        *(u32x4*)(A_HI + 4096 + ao) = ph1;
        *(u32x4*)(A_LO + ao) = pl0;
        *(u32x4*)(A_LO + 4096 + ao) = pl1;
        __syncthreads();
        if (kt < 15) {
          long g = g0 + (kt + 1) * 64;
          ph0 = *(const u32x4*)(Ah + g);
          ph1 = *(const u32x4*)(Ah + g + 32);
          pl0 = *(const u32x4*)(Al + g);
          pl1 = *(const u32x4*)(Al + g + 32);
        }
#pragma unroll
        for (int sub = 0; sub < 2; ++sub) {
          const int stw = (kt * 2 + sub) * 2048;
          const int sta = sub * 4096;
          bf16x8 aH[2], aL[2], bH, bL;
#pragma unroll
          for (int mi = 0; mi < 2; ++mi) {
            int rr = (wm << 5) + (mi << 4) + l15;
            int off = rr * 64 + ((kq ^ (rr & 3)) << 4);
            aH[mi] = *(const bf16x8*)(A_HI + sta + off);
            aL[mi] = *(const bf16x8*)(A_LO + sta + off);
          }
          {
            int c = (wn << 4) + l15;
            int off = c * 64 + ((kq ^ (c & 3)) << 4);
            bH = *(const bf16x8*)(W_HI + stw + off);
            bL = *(const bf16x8*)(W_LO + stw + off);
          }
#pragma unroll
          for (int mi = 0; mi < 2; ++mi) {
            acc[mi] = __builtin_amdgcn_mfma_f32_16x16x32_bf16(aH[mi], bH, acc[mi], 0, 0, 0);
            acc[mi] = __builtin_amdgcn_mfma_f32_16x16x32_bf16(aL[mi], bH, acc[mi], 0, 0, 0);
            acc[mi] = __builtin_amdgcn_mfma_f32_16x16x32_bf16(aH[mi], bL, acc[mi], 0, 0, 0);
          }
        }
      }
      // wait for all 256 ctxp jobs of this step (partly hidden under GEMM)
      if (tid == 0) {
        unsigned target = 256u * (unsigned)(t + 1);
        while (__hip_atomic_load(cdone, __ATOMIC_RELAXED, __HIP_MEMORY_SCOPE_AGENT) < target)
          __builtin_amdgcn_s_sleep(1);
      }
      __syncthreads();
      float* cf = (float*)(L + 131072);
#pragma unroll
      for (int mi = 0; mi < 2; ++mi)
#pragma unroll
        for (int e = 0; e < 4; ++e) {
          int rr = (wm << 5) + (mi << 4) + (kq << 2) + e;
          int cc = (wn << 4) + l15;
          float a = 0.f;
#pragma unroll
          for (int qq = 0; qq < 4; ++qq)
            a += __uint_as_float(aload_u32(ctxp + (((long)(rr << 2) + qq) << 10) + n0 + cc));
          float v = tanhf(acc[mi][e] + a);
          if (t == T_ - 1) dout[CTF_OFF + (long)rr * 1024 + n0 + cc] = v;
          cf[rr * 32 + cc] = v;
        }
      __syncthreads();
#pragma unroll
      for (int qq2 = 0; qq2 < 2; ++qq2) {
        int g = tid + qq2 * 256;
        int b = g >> 3, colg = g & 7;
        u64 ph = 0, pl = 0;
#pragma unroll
        for (int ii = 0; ii < 4; ++ii) {
          float v = cf[b * 32 + colg * 4 + ii];
          u16 hi, lo;
          split2(v, &hi, &lo);
          ph |= (u64)hi << (16 * ii);
          pl |= (u64)lo << (16 * ii);
        }
        long o = (long)(t + 1) * 65536 + (long)b * 1024 + n0 + colg * 4;
        astore_u64(dctx_h + o, ph);
        astore_u64(dctx_l + o, pl);
      }
    } else {
      // Ph2c jobs: blocks 0..191 -> job bx; 224..255 -> job bx-32;
      // blocks 0..31 also do job bx+224.
      int j1 = (bx < 192) ? bx : (bx - 32);
      int njobs = (bx < 32) ? 2 : 1;
      for (int jz = 0; jz < njobs; ++jz) {
        int jj = (jz == 0) ? j1 : (bx + 224);
        int b = jj >> 2, q = jj & 3;
        if (tid < 64) {
          int s = tid;
          float v = 0.f;
#pragma unroll
          for (int qq = 0; qq < 4; ++qq)
            v += __uint_as_float(aload_u32(psc + (((b << 2) + qq) << 6) + s));
          int len = xs_len[b];
          if (s >= len || v == 0.0f) v = -1e10f;
          float m = v;
#pragma unroll
          for (int off = 32; off; off >>= 1) m = fmaxf(m, __shfl_xor(m, off));
          float p = expf(v - m);
          float sum = p;
#pragma unroll
          for (int off = 32; off; off >>= 1) sum += __shfl_xor(sum, off);
          float a = p / sum;
          at_s[s] = a;
          if (q == 0) dout[ATT_OFF + ((long)b * T_ + t) * S_ + s] = a;
        }
        __syncthreads();
        {
          const float* lp = encL + (((long)b * 64 + (q << 4)) << 10) + tid * 4;
          float c0 = 0.f, c1 = 0.f, c2 = 0.f, c3 = 0.f;
#pragma unroll
          for (int s2 = 0; s2 < 16; ++s2) {
            float a = at_s[(q << 4) + s2];
            float4 e = *(const float4*)(lp + (s2 << 10));
            c0 += a * e.x; c1 += a * e.y; c2 += a * e.z; c3 += a * e.w;
          }
          u64 w0 = ((u64)__float_as_uint(c1) << 32) | __float_as_uint(c0);
          u64 w1 = ((u64)__float_as_uint(c3) << 32) | __float_as_uint(c2);
          long o = (((long)(b << 2) + q) << 10) + tid * 4;
          astore_u64(ctxp + o, w0);
          astore_u64(ctxp + o + 2, w1);
        }
        __syncthreads();
        if (tid == 0)
          __hip_atomic_fetch_add(cdone, 1u, __ATOMIC_RELEASE,
                                 __HIP_MEMORY_SCOPE_AGENT);
      }
    }
    if (t < T_ - 1) { gridbar(flags, seq); }
    seq++;
  }
}

// ---------------- log-softmax: combine partials + subtract pass ----------------
__launch_bounds__(256)
__global__ void k_lsm(float* __restrict__ dout, const float2* __restrict__ psum) {
  int R = blockIdx.x;
  long base = (long)R * V_;
  int gm = ((R & 31) << 6) + (R >> 5);
  const float2* pp = psum + ((long)gm << 8);
  int tid = threadIdx.x;
  float m = -3.0e38f, s = 0.f;
  if (tid < 250) {
    float2 p = pp[tid];
    m = p.x;
    s = p.y;
  }
#pragma unroll
  for (int off = 32; off; off >>= 1) {
    float mo = __shfl_xor(m, off), so = __shfl_xor(s, off);
    lse_comb(m, s, mo, so);
  }
  __shared__ float ms[4], ss[4];
  if ((tid & 63) == 0) { ms[tid >> 6] = m; ss[tid >> 6] = s; }
  __syncthreads();
  float M = ms[0], S = ss[0];
  for (int w2 = 1; w2 < 4; ++w2) lse_comb(M, S, ms[w2], ss[w2]);
  float logden = M + logf(S);
  float4* q4 = (float4*)(dout + base);
#pragma unroll 4
  for (int it = 0; it < 31; ++it) {
    float4 x = q4[it * 256 + tid];
    x.x -= logden; x.y -= logden; x.z -= logden; x.w -= logden;
    q4[it * 256 + tid] = x;
  }
  if (tid < 64) {
    float4 x = q4[7936 + tid];
    x.x -= logden; x.y -= logden; x.z -= logden; x.w -= logden;
    q4[7936 + tid] = x;
  }
}

// ---------------- host launcher ----------------
extern "C" void kernel_launch(void* const* d_in, const int* in_sizes, int n_in,
                              void* d_out, int out_size, void* d_ws, size_t ws_size,
                              hipStream_t stream) {
  (void)in_sizes; (void)n_in; (void)out_size;
  const int* input = (const int*)d_in[0];
  const float* memory = (const float*)d_in[1];
  const float* enc = (const float*)d_in[2];
  const int* xs_len = (const int*)d_in[3];
  const float* emb = (const float*)d_in[4];
  const float* wih = (const float*)d_in[5];
  const float* whh = (const float*)d_in[6];
  const float* bih = (const float*)d_in[7];
  const float* bhh = (const float*)d_in[8];
  const float* l1 = (const float*)d_in[9];
  const float* l2 = (const float*)d_in[10];
  const float* wout = (const float*)d_in[11];
  const float* bout = (const float*)d_in[12];
  float* out = (float*)d_out;
  char* w = (char*)d_ws;

  size_t off = 0;
  auto alloc = [&](size_t bytes) {
    size_t o = off;
    off = (off + bytes + 255) & ~(size_t)255;
    return o;
  };
  const size_t N_WIH = 3072UL * 2048, N_WHH = 3072UL * 1024, N_L2 = 1024UL * 2048;
  const size_t N_L1 = 1024UL * 1024, N_ENC = 4096UL * 1024, N_WOUT = 32000UL * 1024;
  const size_t N_EMBX = 2048UL * 1024, N_ENCT = 4096UL * 1024;
  const size_t N_EMBI = 2048UL * 3072, N_ROT = 33UL * 65536;

  size_t o_wih_h = alloc(2 * N_WIH), o_wih_l = alloc(2 * N_WIH);
  size_t o_whh_h = alloc(2 * N_WHH), o_whh_l = alloc(2 * N_WHH);
  size_t o_l2_h = alloc(2 * N_L2), o_l2_l = alloc(2 * N_L2);
  size_t o_l1t_h = alloc(2 * N_L1), o_l1t_l = alloc(2 * N_L1);
  size_t o_ctx_h = alloc(2 * N_ROT), o_ctx_l = alloc(2 * N_ROT);
  size_t o_hh = alloc(2 * N_ROT), o_hl = alloc(2 * N_ROT);
  size_t o_gip = alloc(4 * 2 * 196608), o_ghp = alloc(4 * 2 * 196608);
  size_t o_psc = alloc(4 * 16384);
  size_t o_ctxp = alloc(4 * 262144);
  size_t o_psum = alloc(8UL * 2048 * 256);
  size_t o_bar = alloc(16384);
  size_t o_arena = alloc(2 * N_ENC * 2 + 2 * N_EMBX * 2 + 4 * N_EMBI + 4 * N_ENCT * 2);

  if (off > ws_size) {
    k_guard<<<1, 1, 0, stream>>>(out, 1.0e8f + (float)(ws_size >> 20));
    return;
  }

  u16* wih_h = (u16*)(w + o_wih_h);   u16* wih_l = (u16*)(w + o_wih_l);
  u16* whh_h = (u16*)(w + o_whh_h);   u16* whh_l = (u16*)(w + o_whh_l);
  u16* l2_h = (u16*)(w + o_l2_h);     u16* l2_l = (u16*)(w + o_l2_l);
  u16* l1t_h = (u16*)(w + o_l1t_h);   u16* l1t_l = (u16*)(w + o_l1t_l);
  u16* ctx_h = (u16*)(w + o_ctx_h);   u16* ctx_l = (u16*)(w + o_ctx_l);
  u16* hh_r = (u16*)(w + o_hh);       u16* hl_r = (u16*)(w + o_hl);
  float* gip = (float*)(w + o_gip);
  float* ghp = (float*)(w + o_ghp);
  float* psc = (float*)(w + o_psc);
  float* ctxp = (float*)(w + o_ctxp);
  float2* psum = (float2*)(w + o_psum);
  unsigned* flags = (unsigned*)(w + o_bar);

  char* ar = w + o_arena;
  u16* enc_h = (u16*)ar;
  u16* enc_l = (u16*)(ar + 2 * N_ENC);
  u16* embx_h = (u16*)(ar + 4 * N_ENC);
  u16* embx_l = (u16*)(ar + 4 * N_ENC + 2 * N_EMBX);
  float* embi = (float*)(ar + 4 * N_ENC + 4 * N_EMBX);
  float* encT = (float*)(ar + 4 * N_ENC + 4 * N_EMBX + 4 * N_EMBI);
  float* encL = (float*)(ar + 4 * N_ENC + 4 * N_EMBX + 4 * N_EMBI + 4 * N_ENCT);
  u16* wout_b = (u16*)ar;  // overlays prep arena after k_rec

  hipFuncSetAttribute((const void*)k_rec, hipFuncAttributeMaxDynamicSharedMemorySize,
                      LDS_BYTES);

  // prep (fused splits)
  k_split4<<<4096, 256, 0, stream>>>(wih, wih_h, wih_l, (int)N_WIH,
                                     whh, whh_h, whh_l, (int)N_WHH,
                                     l2, l2_h, l2_l, (int)N_L2,
                                     enc, enc_h, enc_l, (int)N_ENC);
  k_l1t<<<256, 256, 0, stream>>>(l1, l1t_h, l1t_l);
  k_embx<<<2048, 256, 0, stream>>>(input, emb, embx_h, embx_l);
  k_h0<<<256, 256, 0, stream>>>(memory, hh_r, hl_r);
  hipMemsetAsync(ctx_h, 0, 131072, stream);
  hipMemsetAsync(ctx_l, 0, 131072, stream);
  hipMemsetAsync(flags, 0, 16384, stream);

  // encT = enc @ l1 ; encL = enc @ l2a^T ; embi = embx @ w_ih[:, :1024]^T
  k_gemmG<<<256, 256, 0, stream>>>(enc_h, enc_l, l1t_h, l1t_l, encT,
                                   32, 1024, 1024, 1024);
  k_gemmG<<<256, 256, 0, stream>>>(enc_h, enc_l, l2_h, l2_l, encL,
                                   32, 1024, 2048, 1024);
  k_gemmG<<<384, 256, 0, stream>>>(embx_h, embx_l, wih_h, wih_l, embi,
                                   16, 1024, 2048, 3072);

  // persistent recurrence (3 barriers/step, flag-merged Ph2c/Ph3)
  k_rec<<<NB_, 256, LDS_BYTES, stream>>>(embi, ctx_h, ctx_l, hh_r, hl_r, memory,
                                         wih_h, wih_l, whh_h, whh_l, l2_h, l2_l,
                                         gip, ghp, psc, ctxp, encT, encL,
                                         xs_len, bih, bhh, out, flags);

  // wout -> bf16 (overlays dead prep arena)
  k_tobf<<<4096, 256, 0, stream>>>(wout, wout_b, (int)N_WOUT);

  // logits GEMM (gll16 staging, XCD-contiguous nt) + partial LSE
  k_gemmL<<<4000, 256, 0, stream>>>(ctx_h + 65536, wout_b, bout, out, psum);

  // log-softmax: combine partials, subtract in place
  k_lsm<<<2048, 256, 0, stream>>>(out, psum);
}

// Round 16
// 1947.276 us; speedup vs baseline: 1.1506x; 1.0652x over previous
//
#include <hip/hip_runtime.h>

// ---------------------------------------------------------------------------
// AttentionDecoder: B=64 T=32 S=64 H=1024 V=32000
// R16 == R12 verbatim (best verified: 1948us, absmax 0.0625).
//  - k_rec: R7-shape persistent recurrence (256 blocks, 4 barriers/step,
//    LDS-resident weights, split-bf16, quarter-sliced attention phases,
//    atomic-producer / rotation-fresh-cached-consumer coherence).
//  - Prep GEMMs (encT/encL/embi): global_load_lds width=16 staging.
//  - Logits GEMM: gll16 staging, XCD-contiguous tiles, fused partial-LSE
//    epilogue -> psum; k_lsm combines partials + subtract pass only.
// Six k_rec structural variants (R8,R9,R10,R13,R14,R15) all regressed;
// this is the empirical optimum of the explored space.
// ---------------------------------------------------------------------------

#define B_ 64
#define T_ 32
#define S_ 64
#define H_ 1024
#define V_ 32000
#define NB_ 256
#define LDS_BYTES 152064

#define HID_OFF 65536000L
#define ATT_OFF 65601536L
#define CTF_OFF 65732608L

typedef __attribute__((ext_vector_type(8))) short bf16x8;
typedef __attribute__((ext_vector_type(4))) float f32x4;
typedef __attribute__((ext_vector_type(4))) unsigned int u32x4;
typedef unsigned short u16;
typedef unsigned long long u64;

__device__ __forceinline__ u16 f2bf(float v) {
  unsigned int u = __float_as_uint(v);
  unsigned int r = (u + 0x7fffu + ((u >> 16) & 1u)) >> 16;  // RNE
  return (u16)r;
}
__device__ __forceinline__ float bf2f(u16 h) {
  return __uint_as_float(((unsigned int)h) << 16);
}
__device__ __forceinline__ void split2(float v, u16* hi, u16* lo) {
  u16 h = f2bf(v);
  *hi = h;
  *lo = f2bf(v - bf2f(h));
}

// ---- coherent-path (agent-scope relaxed atomic) helpers ----
__device__ __forceinline__ u64 aload_u64(const void* p) {
  return __hip_atomic_load((const u64*)p, __ATOMIC_RELAXED, __HIP_MEMORY_SCOPE_AGENT);
}
__device__ __forceinline__ unsigned aload_u32(const void* p) {
  return __hip_atomic_load((const unsigned*)p, __ATOMIC_RELAXED, __HIP_MEMORY_SCOPE_AGENT);
}
__device__ __forceinline__ void astore_u64(void* p, u64 v) {
  __hip_atomic_store((u64*)p, v, __ATOMIC_RELAXED, __HIP_MEMORY_SCOPE_AGENT);
}
__device__ __forceinline__ void astore_f32(float* p, float v) {
  __hip_atomic_store((unsigned*)p, __float_as_uint(v), __ATOMIC_RELAXED,
                     __HIP_MEMORY_SCOPE_AGENT);
}

// ---- async global->LDS (16B/lane; dest = wave-uniform base + lane*16) ----
__device__ __forceinline__ void gll16(const u16* g, u16* l) {
  __builtin_amdgcn_global_load_lds(
      (const __attribute__((address_space(1))) void*)g,
      (__attribute__((address_space(3))) void*)l, 16, 0, 0);
}

// ---------------- conversion / prep kernels ----------------

__global__ void k_split4(const float* __restrict__ sA, u16* __restrict__ hA,
                         u16* __restrict__ lA, int nA,
                         const float* __restrict__ sB, u16* __restrict__ hB,
                         u16* __restrict__ lB, int nB,
                         const float* __restrict__ sC, u16* __restrict__ hC,
                         u16* __restrict__ lC, int nC,
                         const float* __restrict__ sD, u16* __restrict__ hD,
                         u16* __restrict__ lD, int nD) {
  int i = blockIdx.x * blockDim.x + threadIdx.x;
  int stride = gridDim.x * blockDim.x;
  int t1 = nA, t2 = nA + nB, t3 = t2 + nC, total = t3 + nD;
  for (; i < total; i += stride) {
    if (i < t1) split2(sA[i], &hA[i], &lA[i]);
    else if (i < t2) { int j = i - t1; split2(sB[j], &hB[j], &lB[j]); }
    else if (i < t3) { int j = i - t2; split2(sC[j], &hC[j], &lC[j]); }
    else { int j = i - t3; split2(sD[j], &hD[j], &lD[j]); }
  }
}

__global__ void k_tobf(const float* __restrict__ src, u16* __restrict__ dst, int n) {
  int i = blockIdx.x * blockDim.x + threadIdx.x;
  int stride = gridDim.x * blockDim.x;
  for (; i < n; i += stride) dst[i] = f2bf(src[i]);
}

// l1 (H,H) row-major [i][k] -> l1T hi/lo [k][i]
__global__ void k_l1t(const float* __restrict__ l1, u16* __restrict__ hi,
                      u16* __restrict__ lo) {
  __shared__ float tile[64][65];
  int it = blockIdx.x & 15, kt = blockIdx.x >> 4;
  for (int q = 0; q < 16; ++q) {
    int idx = q * 256 + threadIdx.x;
    int r = idx >> 6, c = idx & 63;
    tile[r][c] = l1[(long)(it * 64 + r) * H_ + kt * 64 + c];
  }
  __syncthreads();
  for (int q = 0; q < 16; ++q) {
    int idx = q * 256 + threadIdx.x;
    int r = idx >> 6, c = idx & 63;
    long o = (long)(kt * 64 + r) * H_ + it * 64 + c;
    split2(tile[c][r], &hi[o], &lo[o]);
  }
}

// gather embeddings: embx[t][b][k] hi/lo
__global__ void k_embx(const int* __restrict__ inp, const float* __restrict__ emb,
                       u16* __restrict__ hi, u16* __restrict__ lo) {
  int bt = blockIdx.x;
  int b = bt >> 5, t = bt & 31;
  int id = inp[b * T_ + t];
  const float* src = emb + (long)id * H_;
  long base = (long)(t * B_ + b) * H_;
  for (int k = threadIdx.x; k < H_; k += 256) split2(src[k], &hi[base + k], &lo[base + k]);
}

// h0 -> hh_r/hl_r slot 0
__global__ void k_h0(const float* __restrict__ mem, u16* __restrict__ hh,
                     u16* __restrict__ hl) {
  int i = blockIdx.x * 256 + threadIdx.x;  // 65536
  float v = mem[i];
  split2(v, &hh[i], &hl[i]);
}

__global__ void k_guard(float* out, float v) {
  if (blockIdx.x == 0 && threadIdx.x == 0) out[0] = v;
}

// ------- prep GEMM: 128x128 tile, K=1024, split-bf16, gll16 staging -------
// LDS: [0,8K) A_hi | [8K,16K) B_hi | [16K,24K) A_lo | [24K,32K) B_lo
__launch_bounds__(256)
__global__ void k_gemmG(const u16* __restrict__ Ah, const u16* __restrict__ Al,
                        const u16* __restrict__ Bh, const u16* __restrict__ Bl,
                        float* __restrict__ C, int Mtiles, int Arow, int Brow,
                        int Crow) {
  int bx = blockIdx.x;
  int mt = bx % Mtiles, nt = bx / Mtiles;
  int m0 = mt << 7, n0 = nt << 7;

  __shared__ __attribute__((aligned(16))) u16 lds[4 * 4096];  // 32 KB
  char* L = (char*)lds;
  const int tid = threadIdx.x;
  const int lane = tid & 63, wid = tid >> 6;
  const int wm = wid & 1, wn = wid >> 1;
  const int l15 = lane & 15, kq = lane >> 4;

  // staging: lane i of wave w fills 16B at region + w*1024 + i*16.
  // dest row r = w*16 + i/4 (round0) / +64 (round1); stored slot = i&3;
  // source slot = stored ^ (r&3)  (both-sides swizzle).
  const int r8 = lane >> 2, ss = lane & 3;
  const int rA0 = (wid << 4) + r8, rA1 = rA0 + 64;
  const int sw0 = (ss ^ (rA0 & 3)) << 3, sw1 = (ss ^ (rA1 & 3)) << 3;
  const u16* gAh0 = Ah + (long)(m0 + rA0) * Arow + sw0;
  const u16* gAh1 = Ah + (long)(m0 + rA1) * Arow + sw1;
  const u16* gAl0 = Al + (long)(m0 + rA0) * Arow + sw0;
  const u16* gAl1 = Al + (long)(m0 + rA1) * Arow + sw1;
  const u16* gBh0 = Bh + (long)(n0 + rA0) * Brow + sw0;
  const u16* gBh1 = Bh + (long)(n0 + rA1) * Brow + sw1;
  const u16* gBl0 = Bl + (long)(n0 + rA0) * Brow + sw0;
  const u16* gBl1 = Bl + (long)(n0 + rA1) * Brow + sw1;
  u16* dAh0 = (u16*)(L + (wid << 10));
  u16* dAh1 = (u16*)(L + 4096 + (wid << 10));
  u16* dBh0 = (u16*)(L + 8192 + (wid << 10));
  u16* dBh1 = (u16*)(L + 12288 + (wid << 10));
  u16* dAl0 = (u16*)(L + 16384 + (wid << 10));
  u16* dAl1 = (u16*)(L + 20480 + (wid << 10));
  u16* dBl0 = (u16*)(L + 24576 + (wid << 10));
  u16* dBl1 = (u16*)(L + 28672 + (wid << 10));

  f32x4 acc[4][4];
  const f32x4 z4 = {0.f, 0.f, 0.f, 0.f};
#pragma unroll
  for (int i = 0; i < 4; ++i)
#pragma unroll
    for (int j = 0; j < 4; ++j) acc[i][j] = z4;

  for (int kt = 0; kt < 32; ++kt) {
    __syncthreads();
    int ko = kt << 5;
    gll16(gAh0 + ko, dAh0);
    gll16(gAh1 + ko, dAh1);
    gll16(gBh0 + ko, dBh0);
    gll16(gBh1 + ko, dBh1);
    gll16(gAl0 + ko, dAl0);
    gll16(gAl1 + ko, dAl1);
    gll16(gBl0 + ko, dBl0);
    gll16(gBl1 + ko, dBl1);
    __syncthreads();
    bf16x8 aH[4], bH[4], aL[4], bL[4];
#pragma unroll
    for (int mi = 0; mi < 4; ++mi) {
      int r = (wm << 6) + (mi << 4) + l15;
      int off = r * 64 + ((kq ^ (r & 3)) << 4);
      aH[mi] = *(const bf16x8*)(L + off);
      aL[mi] = *(const bf16x8*)(L + 16384 + off);
    }
#pragma unroll
    for (int ni = 0; ni < 4; ++ni) {
      int c = (wn << 6) + (ni << 4) + l15;
      int off = c * 64 + ((kq ^ (c & 3)) << 4);
      bH[ni] = *(const bf16x8*)(L + 8192 + off);
      bL[ni] = *(const bf16x8*)(L + 24576 + off);
    }
#pragma unroll
    for (int mi = 0; mi < 4; ++mi)
#pragma unroll
      for (int ni = 0; ni < 4; ++ni) {
        acc[mi][ni] = __builtin_amdgcn_mfma_f32_16x16x32_bf16(aH[mi], bH[ni], acc[mi][ni], 0, 0, 0);
        acc[mi][ni] = __builtin_amdgcn_mfma_f32_16x16x32_bf16(aL[mi], bH[ni], acc[mi][ni], 0, 0, 0);
        acc[mi][ni] = __builtin_amdgcn_mfma_f32_16x16x32_bf16(aH[mi], bL[ni], acc[mi][ni], 0, 0, 0);
      }
  }
#pragma unroll
  for (int mi = 0; mi < 4; ++mi)
#pragma unroll
    for (int ni = 0; ni < 4; ++ni)
#pragma unroll
      for (int e = 0; e < 4; ++e) {
        int r = (wm << 6) + (mi << 4) + (kq << 2) + e;
        int c = (wn << 6) + (ni << 4) + l15;
        C[(long)(m0 + r) * Crow + n0 + c] = acc[mi][ni][e];
      }
}

__device__ __forceinline__ void lse_comb(float& m, float& s, float mo, float so) {
  float M = fmaxf(m, mo);
  s = s * __expf(m - M) + so * __expf(mo - M);
  m = M;
}

// ---------------- logits GEMM + partial-LSE epilogue ----------------
__launch_bounds__(256)
__global__ void k_gemmL(const u16* __restrict__ A, const u16* __restrict__ Bw,
                        const float* __restrict__ bias, float* __restrict__ C,
                        float2* __restrict__ psum) {
  int bx = blockIdx.x;
  int wg = (bx & 7) * 500 + (bx >> 3);  // XCD-contiguous
  int mt = wg & 15, nt = wg >> 4;
  int m0 = mt << 7, n0 = nt << 7;

  __shared__ __attribute__((aligned(16))) u16 lds[2 * 4096];  // 16 KB
  __shared__ float2 lsep[128][2];
  char* L = (char*)lds;
  const int tid = threadIdx.x;
  const int lane = tid & 63, wid = tid >> 6;
  const int wm = wid & 1, wn = wid >> 1;
  const int l15 = lane & 15, kq = lane >> 4;

  const int r8 = lane >> 2, ss = lane & 3;
  const int rA0 = (wid << 4) + r8, rA1 = rA0 + 64;
  const u16* gA0 = A + (long)(m0 + rA0) * 1024 + ((ss ^ (rA0 & 3)) << 3);
  const u16* gA1 = A + (long)(m0 + rA1) * 1024 + ((ss ^ (rA1 & 3)) << 3);
  const u16* gB0 = Bw + (long)(n0 + rA0) * 1024 + ((ss ^ (rA0 & 3)) << 3);
  const u16* gB1 = Bw + (long)(n0 + rA1) * 1024 + ((ss ^ (rA1 & 3)) << 3);
  u16* lA0 = (u16*)(L + (wid << 10));
  u16* lA1 = (u16*)(L + 4096 + (wid << 10));
  u16* lB0 = (u16*)(L + 8192 + (wid << 10));
  u16* lB1 = (u16*)(L + 12288 + (wid << 10));

  f32x4 acc[4][4];
  const f32x4 z4 = {0.f, 0.f, 0.f, 0.f};
#pragma unroll
  for (int i = 0; i < 4; ++i)
#pragma unroll
    for (int j = 0; j < 4; ++j) acc[i][j] = z4;

  for (int kt = 0; kt < 32; ++kt) {
    __syncthreads();
    gll16(gA0 + (kt << 5), lA0);
    gll16(gA1 + (kt << 5), lA1);
    gll16(gB0 + (kt << 5), lB0);
    gll16(gB1 + (kt << 5), lB1);
    __syncthreads();
    bf16x8 aF[4], bF[4];
#pragma unroll
    for (int mi = 0; mi < 4; ++mi) {
      int r = (wm << 6) + (mi << 4) + l15;
      aF[mi] = *(const bf16x8*)(L + r * 64 + ((kq ^ (r & 3)) << 4));
    }
#pragma unroll
    for (int ni = 0; ni < 4; ++ni) {
      int c = (wn << 6) + (ni << 4) + l15;
      bF[ni] = *(const bf16x8*)(L + 8192 + c * 64 + ((kq ^ (c & 3)) << 4));
    }
#pragma unroll
    for (int mi = 0; mi < 4; ++mi)
#pragma unroll
      for (int ni = 0; ni < 4; ++ni)
        acc[mi][ni] = __builtin_amdgcn_mfma_f32_16x16x32_bf16(aF[mi], bF[ni], acc[mi][ni], 0, 0, 0);
  }
  // epilogue: bias + scatter + per-row partial LSE
  float b4[4];
#pragma unroll
  for (int ni = 0; ni < 4; ++ni) b4[ni] = bias[n0 + (wn << 6) + (ni << 4) + l15];
#pragma unroll
  for (int mi = 0; mi < 4; ++mi)
#pragma unroll
    for (int e = 0; e < 4; ++e) {
      int r = (wm << 6) + (mi << 4) + (kq << 2) + e;
      int gm = m0 + r;
      float vv[4], vm = -3.0e38f, vs = 0.f;
#pragma unroll
      for (int ni = 0; ni < 4; ++ni) {
        vv[ni] = acc[mi][ni][e] + b4[ni];
        vm = fmaxf(vm, vv[ni]);
      }
#pragma unroll
      for (int ni = 0; ni < 4; ++ni) {
        vs += __expf(vv[ni] - vm);
        int gn = n0 + (wn << 6) + (ni << 4) + l15;
        C[((long)(gm & 63) * T_ + (gm >> 6)) * V_ + gn] = vv[ni];
      }
#pragma unroll
      for (int o = 1; o < 16; o <<= 1) {
        float mo = __shfl_xor(vm, o), so = __shfl_xor(vs, o);
        lse_comb(vm, vs, mo, so);
      }
      if (l15 == 0) lsep[r][wn] = make_float2(vm, vs);
    }
  __syncthreads();
  if (tid < 128) {
    float2 a = lsep[tid][0], b2 = lsep[tid][1];
    float M = a.x, S = a.y;
    lse_comb(M, S, b2.x, b2.y);
    psum[((long)(m0 + tid) << 8) + nt] = make_float2(M, S);
  }
}

// ---------------- grid barrier (R7 verbatim) ----------------
__device__ __forceinline__ void gridbar(unsigned* flags, unsigned seq) {
  __syncthreads();
  if (threadIdx.x == 0)
    __hip_atomic_store(flags + blockIdx.x * 16, seq, __ATOMIC_RELEASE,
                       __HIP_MEMORY_SCOPE_AGENT);
  if (threadIdx.x < 64) {
    int l = threadIdx.x;
    for (;;) {
      unsigned a = __hip_atomic_load(flags + l * 16, __ATOMIC_RELAXED, __HIP_MEMORY_SCOPE_AGENT);
      unsigned b = __hip_atomic_load(flags + (l + 64) * 16, __ATOMIC_RELAXED, __HIP_MEMORY_SCOPE_AGENT);
      unsigned c = __hip_atomic_load(flags + (l + 128) * 16, __ATOMIC_RELAXED, __HIP_MEMORY_SCOPE_AGENT);
      unsigned d = __hip_atomic_load(flags + (l + 192) * 16, __ATOMIC_RELAXED, __HIP_MEMORY_SCOPE_AGENT);
      if (__all((a >= seq) & (b >= seq) & (c >= seq) & (d >= seq))) break;
      __builtin_amdgcn_s_sleep(1);
    }
  }
  __syncthreads();
}

// ---------------- persistent recurrence kernel (R7 verbatim) ----------------
__launch_bounds__(256)
__global__ void k_rec(const float* __restrict__ embi,
                      u16* __restrict__ dctx_h, u16* __restrict__ dctx_l,
                      u16* __restrict__ hh_r, u16* __restrict__ hl_r,
                      const float* __restrict__ memory,
                      const u16* __restrict__ wih_h, const u16* __restrict__ wih_l,
                      const u16* __restrict__ whh_h, const u16* __restrict__ whh_l,
                      const u16* __restrict__ l2_h, const u16* __restrict__ l2_l,
                      float* __restrict__ gip, float* __restrict__ ghp,
                      float* __restrict__ psc, float* __restrict__ ctxp,
                      const float* __restrict__ encT, const float* __restrict__ encL,
                      const int* __restrict__ xs_len,
                      const float* __restrict__ bih, const float* __restrict__ bhh,
                      float* __restrict__ dout, unsigned* flags) {
  extern __shared__ __attribute__((aligned(16))) char L[];
  char* W_HI = L;
  char* W_LO = L + 65536;
  char* A_HI = L + 131072;
  char* A_LO = L + 139264;
  float* hq = (float*)(L + 147456);
  float* at_s = (float*)(L + 148480);
  const int bx = blockIdx.x;
  const int tid = threadIdx.x;
  const int lane = tid & 63, wid = tid >> 6;
  const int wm = wid & 1, wn = wid >> 1;
  const int l15 = lane & 15, kq = lane >> 4;
  const f32x4 z4 = {0.f, 0.f, 0.f, 0.f};
  unsigned seq = 1;

  const int isGI = (bx < 96);
  const int isGH = (bx >= 96 && bx < 192);
  const int isL2 = (bx >= 192 && bx < 224);
  const int sb = bx >> 2;
  const int sq = bx & 3;
  int nt = 0, kc = 0, n0 = 0;
  const u16 *Wg_h = nullptr, *Wg_l = nullptr;
  int wrs = 0;
  if (isGI) {
    nt = bx % 48; kc = bx / 48;
    Wg_h = wih_h + 1024 + (long)nt * 64 * 2048 + kc * 512;
    Wg_l = wih_l + 1024 + (long)nt * 64 * 2048 + kc * 512;
    wrs = 2048;
  } else if (isGH) {
    int j2 = bx - 96;
    nt = j2 % 48; kc = j2 / 48;
    Wg_h = whh_h + (long)nt * 64 * 1024 + kc * 512;
    Wg_l = whh_l + (long)nt * 64 * 1024 + kc * 512;
    wrs = 1024;
  } else if (isL2) {
    n0 = (bx - 192) << 5;
    Wg_h = l2_h + 1024 + (long)n0 * 2048;
    Wg_l = l2_l + 1024 + (long)n0 * 2048;
    wrs = 2048;
  }

  if (isGI || isGH) {
    for (int e = tid; e < 4096; e += 256) {
      int st = e >> 8, r = (e >> 2) & 63, slot = e & 3;
      long g = (long)r * wrs + st * 32 + slot * 8;
      int o = st * 4096 + r * 64 + ((slot ^ (r & 3)) << 4);
      *(u32x4*)(W_HI + o) = *(const u32x4*)(Wg_h + g);
      *(u32x4*)(W_LO + o) = *(const u32x4*)(Wg_l + g);
    }
  } else if (isL2) {
    for (int e = tid; e < 4096; e += 256) {
      int st = e >> 7, r = (e >> 2) & 31, slot = e & 3;
      long g = (long)r * wrs + st * 32 + slot * 8;
      int o = st * 2048 + r * 64 + ((slot ^ (r & 3)) << 4);
      *(u32x4*)(W_HI + o) = *(const u32x4*)(Wg_h + g);
      *(u32x4*)(W_LO + o) = *(const u32x4*)(Wg_l + g);
    }
  }
  __syncthreads();

  float hpv = memory[sb * 1024 + sq * 256 + tid];

  const int pr = tid >> 2, ps = tid & 3;
  const int ao = pr * 64 + ((ps ^ (pr & 3)) << 4);

  for (int t = 0; t < T_; ++t) {
    if (isGI || isGH) {
      const u16* Ah;
      const u16* Al;
      float* outp;
      if (isGI) {
        Ah = dctx_h + (long)t * 65536 + kc * 512;
        Al = dctx_l + (long)t * 65536 + kc * 512;
        outp = gip + (long)kc * 196608 + nt * 64;
      } else {
        Ah = hh_r + (long)t * 65536 + kc * 512;
        Al = hl_r + (long)t * 65536 + kc * 512;
        outp = ghp + (long)kc * 196608 + nt * 64;
      }
      const long g0 = (long)pr * 1024 + ps * 8;
      u32x4 ph0 = *(const u32x4*)(Ah + g0);
      u32x4 ph1 = *(const u32x4*)(Ah + g0 + 32);
      u32x4 pl0 = *(const u32x4*)(Al + g0);
      u32x4 pl1 = *(const u32x4*)(Al + g0 + 32);

      f32x4 acc[2][2];
#pragma unroll
      for (int i = 0; i < 2; ++i)
#pragma unroll
        for (int j = 0; j < 2; ++j) acc[i][j] = z4;

      for (int kt = 0; kt < 8; ++kt) {
        __syncthreads();
        *(u32x4*)(A_HI + ao) = ph0;
        *(u32x4*)(A_HI + 4096 + ao) = ph1;
        *(u32x4*)(A_LO + ao) = pl0;
        *(u32x4*)(A_LO + 4096 + ao) = pl1;
        __syncthreads();
        if (kt < 7) {
          long g = g0 + (kt + 1) * 64;
          ph0 = *(const u32x4*)(Ah + g);
          ph1 = *(const u32x4*)(Ah + g + 32);
          pl0 = *(const u32x4*)(Al + g);
          pl1 = *(const u32x4*)(Al + g + 32);
        }
#pragma unroll
        for (int sub = 0; sub < 2; ++sub) {
          const int stw = (kt * 2 + sub) * 4096;
          const int sta = sub * 4096;
          bf16x8 aH[2], aL[2], bH[2], bL[2];
#pragma unroll
          for (int mi = 0; mi < 2; ++mi) {
            int rr = (wm << 5) + (mi << 4) + l15;
            int off = rr * 64 + ((kq ^ (rr & 3)) << 4);
            aH[mi] = *(const bf16x8*)(A_HI + sta + off);
            aL[mi] = *(const bf16x8*)(A_LO + sta + off);
          }
#pragma unroll
          for (int ni = 0; ni < 2; ++ni) {
            int c = (wn << 5) + (ni << 4) + l15;
            int off = c * 64 + ((kq ^ (c & 3)) << 4);
            bH[ni] = *(const bf16x8*)(W_HI + stw + off);
            bL[ni] = *(const bf16x8*)(W_LO + stw + off);
          }
#pragma unroll
          for (int mi = 0; mi < 2; ++mi)
#pragma unroll
            for (int ni = 0; ni < 2; ++ni) {
              acc[mi][ni] = __builtin_amdgcn_mfma_f32_16x16x32_bf16(aH[mi], bH[ni], acc[mi][ni], 0, 0, 0);
              acc[mi][ni] = __builtin_amdgcn_mfma_f32_16x16x32_bf16(aL[mi], bH[ni], acc[mi][ni], 0, 0, 0);
              acc[mi][ni] = __builtin_amdgcn_mfma_f32_16x16x32_bf16(aH[mi], bL[ni], acc[mi][ni], 0, 0, 0);
            }
        }
      }
#pragma unroll
      for (int mi = 0; mi < 2; ++mi)
#pragma unroll
        for (int ni = 0; ni < 2; ++ni)
#pragma unroll
          for (int e = 0; e < 4; ++e) {
            int r = (wm << 5) + (mi << 4) + (kq << 2) + e;
            int c = (wn << 5) + (ni << 4) + l15;
            astore_f32(outp + (long)r * 3072 + c, acc[mi][ni][e]);
          }
    }
    gridbar(flags, seq); seq++;

    {
      const int b = sb, q = sq;
      const int j = (q << 8) + tid;
      const float* eb = embi + ((long)t * 64 + b) * 3072;
      float g0r = __uint_as_float(aload_u32(gip + b * 3072 + j));
      float g1r = __uint_as_float(aload_u32(gip + 196608 + b * 3072 + j));
      float g0z = __uint_as_float(aload_u32(gip + b * 3072 + 1024 + j));
      float g1z = __uint_as_float(aload_u32(gip + 196608 + b * 3072 + 1024 + j));
      float g0n = __uint_as_float(aload_u32(gip + b * 3072 + 2048 + j));
      float g1n = __uint_as_float(aload_u32(gip + 196608 + b * 3072 + 2048 + j));
      float h0r = __uint_as_float(aload_u32(ghp + b * 3072 + j));
      float h1r = __uint_as_float(aload_u32(ghp + 196608 + b * 3072 + j));
      float h0z = __uint_as_float(aload_u32(ghp + b * 3072 + 1024 + j));
      float h1z = __uint_as_float(aload_u32(ghp + 196608 + b * 3072 + 1024 + j));
      float h0n = __uint_as_float(aload_u32(ghp + b * 3072 + 2048 + j));
      float h1n = __uint_as_float(aload_u32(ghp + 196608 + b * 3072 + 2048 + j));
      float ir = eb[j] + g0r + g1r + bih[j];
      float iz = eb[1024 + j] + g0z + g1z + bih[1024 + j];
      float in2 = eb[2048 + j] + g0n + g1n + bih[2048 + j];
      float hr = h0r + h1r + bhh[j];
      float hz = h0z + h1z + bhh[1024 + j];
      float hn = h0n + h1n + bhh[2048 + j];
      float r = 1.f / (1.f + expf(-(ir + hr)));
      float z = 1.f / (1.f + expf(-(iz + hz)));
      float n = tanhf(in2 + r * hn);
      float h = (1.f - z) * n + z * hpv;
      hpv = h;
      hq[tid] = h;
      if (t == T_ - 1) dout[HID_OFF + (long)b * 1024 + j] = h;
      __syncthreads();
      if (tid < 64) {
        u64 ph = 0, pl = 0;
#pragma unroll
        for (int ii = 0; ii < 4; ++ii) {
          u16 hi, lo;
          split2(hq[tid * 4 + ii], &hi, &lo);
          ph |= (u64)hi << (16 * ii);
          pl |= (u64)lo << (16 * ii);
        }
        long o = (long)(t + 1) * 65536 + (long)b * 1024 + (q << 8) + tid * 4;
        astore_u64(hh_r + o, ph);
        astore_u64(hl_r + o, pl);
      }
      {
        int s = tid >> 2, part = tid & 3;
        const float4* ep = (const float4*)(encT + (((long)b * 64 + s) << 10) + (q << 8) + (part << 6));
        const float4* hp = (const float4*)(hq + (part << 6));
        float dot = 0.f;
#pragma unroll
        for (int kk = 0; kk < 16; ++kk) {
          float4 e = ep[kk], a = hp[kk];
          dot += e.x * a.x + e.y * a.y + e.z * a.z + e.w * a.w;
        }
        dot += __shfl_xor(dot, 1);
        dot += __shfl_xor(dot, 2);
        if (part == 0) astore_f32(psc + (((b << 2) + q) << 6) + s, dot);
      }
    }
    gridbar(flags, seq); seq++;

    {
      const int b = sb, q = sq;
      if (tid < 64) {
        int s = tid;
        float v = 0.f;
#pragma unroll
        for (int qq = 0; qq < 4; ++qq)
          v += __uint_as_float(aload_u32(psc + (((b << 2) + qq) << 6) + s));
        int len = xs_len[b];
        if (s >= len || v == 0.0f) v = -1e10f;
        float m = v;
#pragma unroll
        for (int off = 32; off; off >>= 1) m = fmaxf(m, __shfl_xor(m, off));
        float p = expf(v - m);
        float sum = p;
#pragma unroll
        for (int off = 32; off; off >>= 1) sum += __shfl_xor(sum, off);
        float a = p / sum;
        at_s[s] = a;
        if (q == 0) dout[ATT_OFF + ((long)b * T_ + t) * S_ + s] = a;
      }
      __syncthreads();
      {
        const float* lp = encL + (((long)b * 64 + (q << 4)) << 10) + tid * 4;
        float c0 = 0.f, c1 = 0.f, c2 = 0.f, c3 = 0.f;
#pragma unroll
        for (int s2 = 0; s2 < 16; ++s2) {
          float a = at_s[(q << 4) + s2];
          float4 e = *(const float4*)(lp + (s2 << 10));
          c0 += a * e.x; c1 += a * e.y; c2 += a * e.z; c3 += a * e.w;
        }
        u64 w0 = ((u64)__float_as_uint(c1) << 32) | __float_as_uint(c0);
        u64 w1 = ((u64)__float_as_uint(c3) << 32) | __float_as_uint(c2);
        long o = (((long)(b << 2) + q) << 10) + tid * 4;
        astore_u64(ctxp + o, w0);
        astore_u64(ctxp + o + 2, w1);
      }
    }
    gridbar(flags, seq); seq++;

    if (isL2) {
      const u16* Ah = hh_r + (long)(t + 1) * 65536;
      const u16* Al = hl_r + (long)(t + 1) * 65536;
      const long g0 = (long)pr * 1024 + ps * 8;
      u32x4 ph0 = *(const u32x4*)(Ah + g0);
      u32x4 ph1 = *(const u32x4*)(Ah + g0 + 32);
      u32x4 pl0 = *(const u32x4*)(Al + g0);
      u32x4 pl1 = *(const u32x4*)(Al + g0 + 32);

      f32x4 acc[2];
      acc[0] = z4; acc[1] = z4;
      for (int kt = 0; kt < 16; ++kt) {
        __syncthreads();
        *(u32x4*)(A_HI + ao) = ph0;
        *(u32x4*)(A_HI + 4096 + ao) = ph1;
        *(u32x4*)(A_LO + ao) = pl0;
        *(u32x4*)(A_LO + 4096 + ao) = pl1;
        __syncthreads();
        if (kt < 15) {
          long g = g0 + (kt + 1) * 64;
          ph0 = *(const u32x4*)(Ah + g);
          ph1 = *(const u32x4*)(Ah + g + 32);
          pl0 = *(const u32x4*)(Al + g);
          pl1 = *(const u32x4*)(Al + g + 32);
        }
#pragma unroll
        for (int sub = 0; sub < 2; ++sub) {
          const int stw = (kt * 2 + sub) * 2048;
          const int sta = sub * 4096;
          bf16x8 aH[2], aL[2], bH, bL;
#pragma unroll
          for (int mi = 0; mi < 2; ++mi) {
            int rr = (wm << 5) + (mi << 4) + l15;
            int off = rr * 64 + ((kq ^ (rr & 3)) << 4);
            aH[mi] = *(const bf16x8*)(A_HI + sta + off);
            aL[mi] = *(const bf16x8*)(A_LO + sta + off);
          }
          {
            int c = (wn << 4) + l15;
            int off = c * 64 + ((kq ^ (c & 3)) << 4);
            bH = *(const bf16x8*)(W_HI + stw + off);
            bL = *(const bf16x8*)(W_LO + stw + off);
          }
#pragma unroll
          for (int mi = 0; mi < 2; ++mi) {
            acc[mi] = __builtin_amdgcn_mfma_f32_16x16x32_bf16(aH[mi], bH, acc[mi], 0, 0, 0);
            acc[mi] = __builtin_amdgcn_mfma_f32_16x16x32_bf16(aL[mi], bH, acc[mi], 0, 0, 0);
            acc[mi] = __builtin_amdgcn_mfma_f32_16x16x32_bf16(aH[mi], bL, acc[mi], 0, 0, 0);
          }
        }
      }
      __syncthreads();
      float* cf = (float*)(L + 131072);
#pragma unroll
      for (int mi = 0; mi < 2; ++mi)
#pragma unroll
        for (int e = 0; e < 4; ++e) {
          int rr = (wm << 5) + (mi << 4) + (kq << 2) + e;
          int cc = (wn << 4) + l15;
          float a = 0.f;
#pragma unroll
          for (int qq = 0; qq < 4; ++qq)
            a += __uint_as_float(aload_u32(ctxp + (((long)(rr << 2) + qq) << 10) + n0 + cc));
          float v = tanhf(acc[mi][e] + a);
          if (t == T_ - 1) dout[CTF_OFF + (long)rr * 1024 + n0 + cc] = v;
          cf[rr * 32 + cc] = v;
        }
      __syncthreads();
#pragma unroll
      for (int qq2 = 0; qq2 < 2; ++qq2) {
        int g = tid + qq2 * 256;
        int b = g >> 3, colg = g & 7;
        u64 ph = 0, pl = 0;
#pragma unroll
        for (int ii = 0; ii < 4; ++ii) {
          float v = cf[b * 32 + colg * 4 + ii];
          u16 hi, lo;
          split2(v, &hi, &lo);
          ph |= (u64)hi << (16 * ii);
          pl |= (u64)lo << (16 * ii);
        }
        long o = (long)(t + 1) * 65536 + (long)b * 1024 + n0 + colg * 4;
        astore_u64(dctx_h + o, ph);
        astore_u64(dctx_l + o, pl);
      }
    }
    if (t < T_ - 1) { gridbar(flags, seq); }
    seq++;
  }
}

// ---------------- log-softmax: combine partials + subtract pass ----------------
__launch_bounds__(256)
__global__ void k_lsm(float* __restrict__ dout, const float2* __restrict__ psum) {
  int R = blockIdx.x;  // output row = b*T + t
  long base = (long)R * V_;
  int gm = ((R & 31) << 6) + (R >> 5);
  const float2* pp = psum + ((long)gm << 8);
  int tid = threadIdx.x;
  float m = -3.0e38f, s = 0.f;
  if (tid < 250) {
    float2 p = pp[tid];
    m = p.x;
    s = p.y;
  }
#pragma unroll
  for (int off = 32; off; off >>= 1) {
    float mo = __shfl_xor(m, off), so = __shfl_xor(s, off);
    lse_comb(m, s, mo, so);
  }
  __shared__ float ms[4], ss[4];
  if ((tid & 63) == 0) { ms[tid >> 6] = m; ss[tid >> 6] = s; }
  __syncthreads();
  float M = ms[0], S = ss[0];
  for (int w2 = 1; w2 < 4; ++w2) lse_comb(M, S, ms[w2], ss[w2]);
  float logden = M + logf(S);
  float4* q4 = (float4*)(dout + base);
#pragma unroll 4
  for (int it = 0; it < 31; ++it) {
    float4 x = q4[it * 256 + tid];
    x.x -= logden; x.y -= logden; x.z -= logden; x.w -= logden;
    q4[it * 256 + tid] = x;
  }
  if (tid < 64) {
    float4 x = q4[7936 + tid];
    x.x -= logden; x.y -= logden; x.z -= logden; x.w -= logden;
    q4[7936 + tid] = x;
  }
}

// ---------------- host launcher ----------------
extern "C" void kernel_launch(void* const* d_in, const int* in_sizes, int n_in,
                              void* d_out, int out_size, void* d_ws, size_t ws_size,
                              hipStream_t stream) {
  (void)in_sizes; (void)n_in; (void)out_size;
  const int* input = (const int*)d_in[0];
  const float* memory = (const float*)d_in[1];
  const float* enc = (const float*)d_in[2];
  const int* xs_len = (const int*)d_in[3];
  const float* emb = (const float*)d_in[4];
  const float* wih = (const float*)d_in[5];
  const float* whh = (const float*)d_in[6];
  const float* bih = (const float*)d_in[7];
  const float* bhh = (const float*)d_in[8];
  const float* l1 = (const float*)d_in[9];
  const float* l2 = (const float*)d_in[10];
  const float* wout = (const float*)d_in[11];
  const float* bout = (const float*)d_in[12];
  float* out = (float*)d_out;
  char* w = (char*)d_ws;

  size_t off = 0;
  auto alloc = [&](size_t bytes) {
    size_t o = off;
    off = (off + bytes + 255) & ~(size_t)255;
    return o;
  };
  const size_t N_WIH = 3072UL * 2048, N_WHH = 3072UL * 1024, N_L2 = 1024UL * 2048;
  const size_t N_L1 = 1024UL * 1024, N_ENC = 4096UL * 1024, N_WOUT = 32000UL * 1024;
  const size_t N_EMBX = 2048UL * 1024, N_ENCT = 4096UL * 1024;
  const size_t N_EMBI = 2048UL * 3072, N_ROT = 33UL * 65536;

  size_t o_wih_h = alloc(2 * N_WIH), o_wih_l = alloc(2 * N_WIH);
  size_t o_whh_h = alloc(2 * N_WHH), o_whh_l = alloc(2 * N_WHH);
  size_t o_l2_h = alloc(2 * N_L2), o_l2_l = alloc(2 * N_L2);
  size_t o_l1t_h = alloc(2 * N_L1), o_l1t_l = alloc(2 * N_L1);
  size_t o_ctx_h = alloc(2 * N_ROT), o_ctx_l = alloc(2 * N_ROT);
  size_t o_hh = alloc(2 * N_ROT), o_hl = alloc(2 * N_ROT);
  size_t o_gip = alloc(4 * 2 * 196608), o_ghp = alloc(4 * 2 * 196608);
  size_t o_psc = alloc(4 * 16384);
  size_t o_ctxp = alloc(4 * 262144);
  size_t o_psum = alloc(8UL * 2048 * 256);
  size_t o_bar = alloc(16384);
  size_t o_arena = alloc(2 * N_ENC * 2 + 2 * N_EMBX * 2 + 4 * N_EMBI + 4 * N_ENCT * 2);

  if (off > ws_size) {
    k_guard<<<1, 1, 0, stream>>>(out, 1.0e8f + (float)(ws_size >> 20));
    return;
  }

  u16* wih_h = (u16*)(w + o_wih_h);   u16* wih_l = (u16*)(w + o_wih_l);
  u16* whh_h = (u16*)(w + o_whh_h);   u16* whh_l = (u16*)(w + o_whh_l);
  u16* l2_h = (u16*)(w + o_l2_h);     u16* l2_l = (u16*)(w + o_l2_l);
  u16* l1t_h = (u16*)(w + o_l1t_h);   u16* l1t_l = (u16*)(w + o_l1t_l);
  u16* ctx_h = (u16*)(w + o_ctx_h);   u16* ctx_l = (u16*)(w + o_ctx_l);
  u16* hh_r = (u16*)(w + o_hh);       u16* hl_r = (u16*)(w + o_hl);
  float* gip = (float*)(w + o_gip);
  float* ghp = (float*)(w + o_ghp);
  float* psc = (float*)(w + o_psc);
  float* ctxp = (float*)(w + o_ctxp);
  float2* psum = (float2*)(w + o_psum);
  unsigned* flags = (unsigned*)(w + o_bar);

  char* ar = w + o_arena;
  u16* enc_h = (u16*)ar;
  u16* enc_l = (u16*)(ar + 2 * N_ENC);
  u16* embx_h = (u16*)(ar + 4 * N_ENC);
  u16* embx_l = (u16*)(ar + 4 * N_ENC + 2 * N_EMBX);
  float* embi = (float*)(ar + 4 * N_ENC + 4 * N_EMBX);
  float* encT = (float*)(ar + 4 * N_ENC + 4 * N_EMBX + 4 * N_EMBI);
  float* encL = (float*)(ar + 4 * N_ENC + 4 * N_EMBX + 4 * N_EMBI + 4 * N_ENCT);
  u16* wout_b = (u16*)ar;  // overlays prep arena after k_rec

  hipFuncSetAttribute((const void*)k_rec, hipFuncAttributeMaxDynamicSharedMemorySize,
                      LDS_BYTES);

  // prep (fused splits)
  k_split4<<<4096, 256, 0, stream>>>(wih, wih_h, wih_l, (int)N_WIH,
                                     whh, whh_h, whh_l, (int)N_WHH,
                                     l2, l2_h, l2_l, (int)N_L2,
                                     enc, enc_h, enc_l, (int)N_ENC);
  k_l1t<<<256, 256, 0, stream>>>(l1, l1t_h, l1t_l);
  k_embx<<<2048, 256, 0, stream>>>(input, emb, embx_h, embx_l);
  k_h0<<<256, 256, 0, stream>>>(memory, hh_r, hl_r);
  hipMemsetAsync(ctx_h, 0, 131072, stream);
  hipMemsetAsync(ctx_l, 0, 131072, stream);
  hipMemsetAsync(flags, 0, 16384, stream);

  // encT = enc @ l1 ; encL = enc @ l2a^T ; embi = embx @ w_ih[:, :1024]^T
  k_gemmG<<<256, 256, 0, stream>>>(enc_h, enc_l, l1t_h, l1t_l, encT,
                                   32, 1024, 1024, 1024);
  k_gemmG<<<256, 256, 0, stream>>>(enc_h, enc_l, l2_h, l2_l, encL,
                                   32, 1024, 2048, 1024);
  k_gemmG<<<384, 256, 0, stream>>>(embx_h, embx_l, wih_h, wih_l, embi,
                                   16, 1024, 2048, 3072);

  // persistent recurrence (R7 verbatim)
  k_rec<<<NB_, 256, LDS_BYTES, stream>>>(embi, ctx_h, ctx_l, hh_r, hl_r, memory,
                                         wih_h, wih_l, whh_h, whh_l, l2_h, l2_l,
                                         gip, ghp, psc, ctxp, encT, encL,
                                         xs_len, bih, bhh, out, flags);

  // wout -> bf16 (overlays dead prep arena)
  k_tobf<<<4096, 256, 0, stream>>>(wout, wout_b, (int)N_WOUT);

  // logits GEMM (gll16 staging, XCD-contiguous nt) + partial LSE
  k_gemmL<<<4000, 256, 0, stream>>>(ctx_h + 65536, wout_b, bout, out, psum);

  // log-softmax: combine partials, subtract in place
  k_lsm<<<2048, 256, 0, stream>>>(out, psum);
}